// Round 12
// baseline (358.371 us; speedup 1.0000x reference)
//
#include <hip/hip_runtime.h>
#include <hip/hip_bf16.h>

// GCN: 3x GCNConv(relu) + mean-pool + linear + log_softmax
// N=100000 nodes, E=1600000 edges, F=128 -> 64 -> 64 -> 64, 256 graphs, 15 classes.
//
// Round 12 structure (= r10 + wide-broadcast GEMM inner loop):
//  - build: zero global atomics (cnt/btot/sscan/cbase/place/finalize), r10-measured
//  - gemm: W in LDS as wl[k*64+lane] (b32, bank=lane%32, conflict-free — r10: 0 conflicts;
//    r11's transposed b128 W-read = 2.4M conflicts, reverted). xt rows read as
//    float4 BROADCAST (same addr across wave = free). 12 LDS instr / 32 FMAs
//    (r10: 36/32 -> 57us LDS-issue bound; r11: 9/32 but 8-way bank conflicts -> 73us)
//  - agg: 8-acc bf16 gather (~gather floor), unchanged
//  - norm folded into gather table: xwb[i] = bf16(dinv[i] * (h@W)[i])

#define N_GRAPHS 256
#define HIDDEN 64
#define N_CLASSES 15
#define TILE_ROWS 32
#define NB_SHIFT 9        // bucket = 512 consecutive nodes
#define MAXNB 256         // supports N <= 131072
#define EDGE_CHUNK 4096   // edges per block in cnt/place (16 per thread)

__device__ __forceinline__ float bf2f(ushort u) {
    return __uint_as_float(((unsigned int)u) << 16);
}
__device__ __forceinline__ ushort f2bf(float f) {
    __hip_bfloat16 h = __float2bfloat16(f);  // RNE
    return *reinterpret_cast<ushort*>(&h);
}

// ---------------- per-(block,bucket) counts (LDS only) ----------------
__global__ __launch_bounds__(256) void cnt_kernel(const int* __restrict__ dst,
                                                  int* __restrict__ cnt, int E, int nblk) {
    __shared__ int lcnt[MAXNB];
    int blk = blockIdx.x;
    for (int i = threadIdx.x; i < MAXNB; i += 256) lcnt[i] = 0;
    __syncthreads();
    int base = blk * EDGE_CHUNK;
#pragma unroll
    for (int it = 0; it < EDGE_CHUNK / 256; ++it) {
        int e = base + it * 256 + threadIdx.x;
        if (e < E) atomicAdd(&lcnt[dst[e] >> NB_SHIFT], 1);
    }
    __syncthreads();
    for (int b = threadIdx.x; b < MAXNB; b += 256) cnt[b * nblk + blk] = lcnt[b];
}

// ---------------- bucket totals ----------------
__global__ __launch_bounds__(256) void btot_kernel(const int* __restrict__ cnt,
                                                   int* __restrict__ btot, int nblk) {
    int b = blockIdx.x;
    __shared__ int ls[256];
    int s = 0;
    for (int i = threadIdx.x; i < nblk; i += 256) s += cnt[b * nblk + i];
    ls[threadIdx.x] = s;
    __syncthreads();
    for (int off = 128; off > 0; off >>= 1) {
        if (threadIdx.x < off) ls[threadIdx.x] += ls[threadIdx.x + off];
        __syncthreads();
    }
    if (threadIdx.x == 0) btot[b] = ls[0];
}

// ---------------- tiny exclusive scan of bucket totals -> sbase[0..nb] ----------------
__global__ __launch_bounds__(256) void sscan_kernel(const int* __restrict__ btot,
                                                    int* __restrict__ sbase, int nb) {
    __shared__ int s[256];
    int t = threadIdx.x;
    s[t] = (t < nb) ? btot[t] : 0;
    __syncthreads();
    for (int off = 1; off < 256; off <<= 1) {
        int v = (t >= off) ? s[t - off] : 0;
        __syncthreads();
        s[t] += v;
        __syncthreads();
    }
    if (t < nb) sbase[t] = (t == 0) ? 0 : s[t - 1];
    if (t == 0) sbase[nb] = s[255];
}

// ---------------- cbase[b][blk] = sbase[b] + excl_scan_blk(cnt[b][:]) ----------------
__global__ __launch_bounds__(256) void cbase_kernel(const int* __restrict__ cnt,
                                                    const int* __restrict__ sbase,
                                                    int* __restrict__ cbase, int nblk) {
    int b = blockIdx.x;
    __shared__ int ls[256];
    int t = threadIdx.x;
    int chunk = (nblk + 255) / 256;
    int start = t * chunk;
    int end = start + chunk;
    if (end > nblk) end = nblk;
    int s = 0;
    for (int i = start; i < end; ++i) s += cnt[b * nblk + i];
    ls[t] = s;
    __syncthreads();
    for (int off = 1; off < 256; off <<= 1) {
        int v = (t >= off) ? ls[t - off] : 0;
        __syncthreads();
        ls[t] += v;
        __syncthreads();
    }
    int run = sbase[b] + ((t == 0) ? 0 : ls[t - 1]);
    for (int i = start; i < end; ++i) {
        cbase[b * nblk + i] = run;
        run += cnt[b * nblk + i];
    }
}

// ---------------- placement: LDS tickets, bucket-major staging ----------------
__global__ __launch_bounds__(256) void place_kernel(const int* __restrict__ src,
                                                    const int* __restrict__ dst,
                                                    const int* __restrict__ cbase,
                                                    int2* __restrict__ stage,
                                                    int E, int nblk, int nb) {
    __shared__ int lpos[MAXNB];
    int blk = blockIdx.x;
    for (int b = threadIdx.x; b < nb; b += 256) lpos[b] = cbase[b * nblk + blk];
    __syncthreads();
    int base = blk * EDGE_CHUNK;
#pragma unroll
    for (int it = 0; it < EDGE_CHUNK / 256; ++it) {
        int e = base + it * 256 + threadIdx.x;
        if (e < E) {
            int d = dst[e], s = src[e];
            int slot = atomicAdd(&lpos[d >> NB_SHIFT], 1);  // LDS ticket
            stage[slot] = make_int2(s, d);
        }
    }
}

// ---------------- finalize: per-bucket deg/rowptr/dinv + CSR col (all bucket-local) ----------------
__global__ __launch_bounds__(256) void finalize_kernel(const int2* __restrict__ stage,
                                                       const int* __restrict__ sbase,
                                                       int* __restrict__ rowptr,
                                                       float* __restrict__ dinv,
                                                       int* __restrict__ col, int n, int nb) {
    int b = blockIdx.x;
    int t = threadIdx.x;
    int node0 = b << NB_SHIFT;
    int lo = sbase[b], hi = sbase[b + 1];

    __shared__ int lcnt[1 << NB_SHIFT];
    __shared__ int lrow[1 << NB_SHIFT];
    __shared__ int ls[256];

    lcnt[t] = 0;
    lcnt[t + 256] = 0;
    __syncthreads();
    // pass 1: local degree histogram
    for (int e = lo + t; e < hi; e += 256) {
        atomicAdd(&lcnt[stage[e].y - node0], 1);
    }
    __syncthreads();
    // local exclusive scan over 512 counters (2 per thread)
    int c0 = lcnt[2 * t], c1 = lcnt[2 * t + 1];
    ls[t] = c0 + c1;
    __syncthreads();
    for (int off = 1; off < 256; off <<= 1) {
        int v = (t >= off) ? ls[t - off] : 0;
        __syncthreads();
        ls[t] += v;
        __syncthreads();
    }
    int bse = (t == 0) ? 0 : ls[t - 1];
    lrow[2 * t] = bse;
    lrow[2 * t + 1] = bse + c0;
    // rowptr / dinv
    int i0 = node0 + 2 * t;
    if (i0 < n) {
        rowptr[i0] = lo + bse;
        dinv[i0] = rsqrtf((float)(c0 + 1));  // +1 = self-loop
    }
    if (i0 + 1 < n) {
        rowptr[i0 + 1] = lo + bse + c0;
        dinv[i0 + 1] = rsqrtf((float)(c1 + 1));
    }
    if (b == nb - 1 && t == 0) rowptr[n] = hi;
    __syncthreads();
    // reset counters for ticketing
    lcnt[t] = 0;
    lcnt[t + 256] = 0;
    __syncthreads();
    // pass 2: place col within this bucket's contiguous window [lo, hi)
    for (int e = lo + t; e < hi; e += 256) {
        int2 sd = stage[e];
        int li = sd.y - node0;
        int k = atomicAdd(&lcnt[li], 1);  // LDS ticket
        col[lo + lrow[li] + k] = sd.x;
    }
}

// ---------------- GEMM: XWB(bf16) = dinv .* (X @ W), tiled ----------------
// block = 256 threads (4 waves). One 32-row tile per block, grid-stride.
// LDS: xt[32][FIN] fp32 + wl[k*64+lane] (r10 layout, conflict-free b32).
// Inner loop per k-quad: 4 wl b32 (bank=lane, clean) + 8 xt float4 BROADCASTS
// (same addr across wave = bank-free) + 32 FMAs. 12 LDS instr/32 FMA
// (r10: 36/32; r11 transposed-W b128: 8-way conflicts — both measured worse).
template <int FIN, typename TIN>
__global__ __launch_bounds__(256) void gemm_tile_kernel(const TIN* __restrict__ X,
                                                        const float* __restrict__ W,
                                                        const float* __restrict__ dinv,
                                                        ushort* __restrict__ XWB, int n) {
    __shared__ float xt[TILE_ROWS][FIN];
    __shared__ float wl[FIN * 64];
    for (int i = threadIdx.x; i < FIN * 64; i += 256) wl[i] = W[i];

    int lane = threadIdx.x & 63;
    int w = threadIdx.x >> 6;
    int ntiles = (n + TILE_ROWS - 1) / TILE_ROWS;

    for (int t = blockIdx.x; t < ntiles; t += gridDim.x) {
        int row0 = t * TILE_ROWS;
        __syncthreads();  // xt reuse guard (also covers initial wl stage)
        if constexpr (sizeof(TIN) == 4) {
            const int NF4 = TILE_ROWS * FIN / 4;  // float4 chunks
            for (int i = threadIdx.x; i < NF4; i += 256) {
                int r = i / (FIN / 4), k4 = i % (FIN / 4);
                int row = row0 + r;
                float4 v;
                if (row < n) v = *reinterpret_cast<const float4*>((const float*)X + (size_t)row * FIN + k4 * 4);
                else v = make_float4(0.f, 0.f, 0.f, 0.f);
                *reinterpret_cast<float4*>(&xt[r][k4 * 4]) = v;
            }
        } else {
            const int NC8 = TILE_ROWS * FIN / 8;  // 8 bf16 = 16B chunks
            for (int i = threadIdx.x; i < NC8; i += 256) {
                int r = i / (FIN / 8), k8 = i % (FIN / 8);
                int row = row0 + r;
                uint4 v = make_uint4(0u, 0u, 0u, 0u);
                if (row < n) v = *reinterpret_cast<const uint4*>((const ushort*)X + (size_t)row * FIN + k8 * 8);
                float* dstp = &xt[r][k8 * 8];
                dstp[0] = bf2f((ushort)(v.x & 0xffff));
                dstp[1] = bf2f((ushort)(v.x >> 16));
                dstp[2] = bf2f((ushort)(v.y & 0xffff));
                dstp[3] = bf2f((ushort)(v.y >> 16));
                dstp[4] = bf2f((ushort)(v.z & 0xffff));
                dstp[5] = bf2f((ushort)(v.z >> 16));
                dstp[6] = bf2f((ushort)(v.w & 0xffff));
                dstp[7] = bf2f((ushort)(v.w >> 16));
            }
        }
        __syncthreads();

        int r0 = w * 8;
        float acc[8] = {0.f, 0.f, 0.f, 0.f, 0.f, 0.f, 0.f, 0.f};
#pragma unroll 4
        for (int kq = 0; kq < FIN / 4; ++kq) {
            int k = kq << 2;
            float w0 = wl[(k + 0) * 64 + lane];
            float w1 = wl[(k + 1) * 64 + lane];
            float w2 = wl[(k + 2) * 64 + lane];
            float w3 = wl[(k + 3) * 64 + lane];
#pragma unroll
            for (int j = 0; j < 8; ++j) {
                float4 xv = *reinterpret_cast<const float4*>(&xt[r0 + j][k]);  // broadcast
                acc[j] += xv.x * w0 + xv.y * w1 + xv.z * w2 + xv.w * w3;
            }
        }
#pragma unroll
        for (int j = 0; j < 8; ++j) {
            int row = row0 + r0 + j;
            if (row < n) XWB[(size_t)row * 64 + lane] = f2bf(dinv[row] * acc[j]);
        }
    }
}

// ---------------- CSR aggregation: h = relu(dinv[i]*(xwb[i] + sum xwb[col]) + b), bf16 out ----------------
__global__ __launch_bounds__(256) void agg_csr_kernel(const ushort* __restrict__ XWB,
                                                      const int* __restrict__ rowptr,
                                                      const int* __restrict__ col,
                                                      const float* __restrict__ dinv,
                                                      const float* __restrict__ bias,
                                                      ushort* __restrict__ OUT, int n) {
    int lane = threadIdx.x & 63;
    int wid = (blockIdx.x * blockDim.x + threadIdx.x) >> 6;
    int nw = (gridDim.x * blockDim.x) >> 6;
    float b = bias[lane];
    for (int i = wid; i < n; i += nw) {
        float a0 = bf2f(XWB[(size_t)i * 64 + lane]);  // self-loop (pre-scaled)
        float a1 = 0.f, a2 = 0.f, a3 = 0.f, a4 = 0.f, a5 = 0.f, a6 = 0.f, a7 = 0.f;
        int p0 = __builtin_amdgcn_readfirstlane(rowptr[i]);
        int p1 = __builtin_amdgcn_readfirstlane(rowptr[i + 1]);
        int p = p0;
        for (; p + 8 <= p1; p += 8) {
            int c0 = col[p], c1 = col[p + 1], c2 = col[p + 2], c3 = col[p + 3];
            int c4 = col[p + 4], c5 = col[p + 5], c6 = col[p + 6], c7 = col[p + 7];
            a0 += bf2f(XWB[(size_t)c0 * 64 + lane]);
            a1 += bf2f(XWB[(size_t)c1 * 64 + lane]);
            a2 += bf2f(XWB[(size_t)c2 * 64 + lane]);
            a3 += bf2f(XWB[(size_t)c3 * 64 + lane]);
            a4 += bf2f(XWB[(size_t)c4 * 64 + lane]);
            a5 += bf2f(XWB[(size_t)c5 * 64 + lane]);
            a6 += bf2f(XWB[(size_t)c6 * 64 + lane]);
            a7 += bf2f(XWB[(size_t)c7 * 64 + lane]);
        }
        for (; p < p1; ++p) {
            a0 += bf2f(XWB[(size_t)col[p] * 64 + lane]);
        }
        float sum = ((a0 + a1) + (a2 + a3)) + ((a4 + a5) + (a6 + a7));
        float acc = dinv[i] * sum + b;
        OUT[(size_t)i * 64 + lane] = f2bf(fmaxf(acc, 0.f));
    }
}

// ---------------- mean pool (batch is sorted; H is bf16) ----------------
__global__ void pool_kernel(const ushort* __restrict__ H, const int* __restrict__ batch,
                            float* __restrict__ pooled, int n) {
    int g = blockIdx.x;
    int lo = 0, hi = n;
    while (lo < hi) { int mid = (lo + hi) >> 1; if (batch[mid] < g) lo = mid + 1; else hi = mid; }
    int start = lo;
    lo = 0; hi = n;
    while (lo < hi) { int mid = (lo + hi) >> 1; if (batch[mid] < g + 1) lo = mid + 1; else hi = mid; }
    int end = lo;

    int lane = threadIdx.x & 63;
    int w = threadIdx.x >> 6;
    __shared__ float part[4][64];
    float acc = 0.f;
    for (int i = start + w; i < end; i += 4) acc += bf2f(H[(size_t)i * 64 + lane]);
    part[w][lane] = acc;
    __syncthreads();
    if (w == 0) {
        float s = part[0][lane] + part[1][lane] + part[2][lane] + part[3][lane];
        float cnt = (float)(end - start);
        pooled[g * 64 + lane] = s / fmaxf(cnt, 1.0f);
    }
}

// ---------------- head ----------------
__global__ void head_kernel(const float* __restrict__ pooled, const float* __restrict__ fcw,
                            const float* __restrict__ fcb, float* __restrict__ out) {
    __shared__ float w[64 * N_CLASSES];
    __shared__ float bb[N_CLASSES];
    for (int i = threadIdx.x; i < 64 * N_CLASSES; i += blockDim.x) w[i] = fcw[i];
    if (threadIdx.x < N_CLASSES) bb[threadIdx.x] = fcb[threadIdx.x];
    __syncthreads();
    int g = threadIdx.x;  // 256 threads, one per graph
    float logits[N_CLASSES];
    float m = -1e30f;
    const float* pr = pooled + g * 64;
    for (int c = 0; c < N_CLASSES; ++c) {
        float acc = bb[c];
        for (int k = 0; k < 64; ++k) acc += pr[k] * w[k * N_CLASSES + c];
        logits[c] = acc;
        m = fmaxf(m, acc);
    }
    float se = 0.f;
    for (int c = 0; c < N_CLASSES; ++c) se += expf(logits[c] - m);
    float lse = m + logf(se);
    for (int c = 0; c < N_CLASSES; ++c) out[g * N_CLASSES + c] = logits[c] - lse;
}

extern "C" void kernel_launch(void* const* d_in, const int* in_sizes, int n_in,
                              void* d_out, int out_size, void* d_ws, size_t ws_size,
                              hipStream_t stream) {
    const float* x    = (const float*)d_in[0];
    const float* w1   = (const float*)d_in[1];
    const float* b1   = (const float*)d_in[2];
    const float* w2   = (const float*)d_in[3];
    const float* b2   = (const float*)d_in[4];
    const float* w3   = (const float*)d_in[5];
    const float* b3   = (const float*)d_in[6];
    const float* fcw  = (const float*)d_in[7];
    const float* fcb  = (const float*)d_in[8];
    const int*   ei   = (const int*)d_in[9];
    const int*   batch = (const int*)d_in[10];

    const int N = in_sizes[10];       // 100000
    const int E = in_sizes[9] / 2;    // 1600000
    const int* src = ei;
    const int* dst = ei + E;

    const int NBUCK = (N + (1 << NB_SHIFT) - 1) >> NB_SHIFT;   // 196
    const int NBLK = (E + EDGE_CHUNK - 1) / EDGE_CHUNK;        // 391

    char* ws = (char*)d_ws;
    size_t off = 0;
    auto alloc = [&](size_t bytes) -> void* {
        void* p = ws + off;
        off += (bytes + 255) & ~(size_t)255;
        return p;
    };
    int*    rowptr = (int*)alloc(((size_t)N + 1) * 4);
    int*    cnt    = (int*)alloc((size_t)MAXNB * NBLK * 4);
    int*    cbase  = (int*)alloc((size_t)MAXNB * NBLK * 4);
    int*    btot   = (int*)alloc(256 * 4);
    int*    sbase  = (int*)alloc(260 * 4);
    int2*   stage  = (int2*)alloc((size_t)E * 8);
    int*    col    = (int*)alloc((size_t)E * 4);
    float*  dinv   = (float*)alloc((size_t)N * 4);
    ushort* xwb    = (ushort*)alloc((size_t)N * 64 * 2);  // bf16 pre-scaled gather table
    ushort* hbuf   = (ushort*)alloc((size_t)N * 64 * 2);  // bf16 h
    float*  pooled = (float*)alloc((size_t)N_GRAPHS * 64 * 4);
    (void)ws_size;

    const int GB = 2048;

    cnt_kernel<<<NBLK, 256, 0, stream>>>(dst, cnt, E, NBLK);
    btot_kernel<<<NBUCK, 256, 0, stream>>>(cnt, btot, NBLK);
    sscan_kernel<<<1, 256, 0, stream>>>(btot, sbase, NBUCK);
    cbase_kernel<<<NBUCK, 256, 0, stream>>>(cnt, sbase, cbase, NBLK);
    place_kernel<<<NBLK, 256, 0, stream>>>(src, dst, cbase, stage, E, NBLK, NBUCK);
    finalize_kernel<<<NBUCK, 256, 0, stream>>>(stage, sbase, rowptr, dinv, col, N, NBUCK);

    int ntiles = (N + TILE_ROWS - 1) / TILE_ROWS;  // 3125

    // layer 1
    gemm_tile_kernel<128, float><<<ntiles, 256, 0, stream>>>(x, w1, dinv, xwb, N);
    agg_csr_kernel<<<GB, 256, 0, stream>>>(xwb, rowptr, col, dinv, b1, hbuf, N);
    // layer 2
    gemm_tile_kernel<64, ushort><<<ntiles, 256, 0, stream>>>(hbuf, w2, dinv, xwb, N);
    agg_csr_kernel<<<GB, 256, 0, stream>>>(xwb, rowptr, col, dinv, b2, hbuf, N);
    // layer 3
    gemm_tile_kernel<64, ushort><<<ntiles, 256, 0, stream>>>(hbuf, w3, dinv, xwb, N);
    agg_csr_kernel<<<GB, 256, 0, stream>>>(xwb, rowptr, col, dinv, b3, hbuf, N);

    pool_kernel<<<N_GRAPHS, 256, 0, stream>>>(hbuf, batch, pooled, N);
    head_kernel<<<1, 256, 0, stream>>>(pooled, fcw, fcb, (float*)d_out);
}

// Round 13
// 275.887 us; speedup vs baseline: 1.2990x; 1.2990x over previous
//
#include <hip/hip_runtime.h>
#include <hip/hip_bf16.h>

// GCN: 3x GCNConv(relu) + mean-pool + linear + log_softmax
// N=100000 nodes, E=1600000 edges, F=128 -> 64 -> 64 -> 64, 256 graphs, 15 classes.
//
// Round 13 structure (= r10 build + MFMA gemm):
//  - build: zero global atomics (cnt/btot/sscan/cbase/place/finalize), r10-measured
//  - gemm: v_mfma_f32_16x16x32_bf16. Wave = 16 rows x 64 cols. A from global
//    (bf16 direct / fp32+convert for layer 1). B = W in LDS, transposed bf16,
//    XOR-swizzled (byte ^= (c&7)<<4) -> ds_read_b128 ~2-way conflicts.
//    VALU+LDS gemm plateaued at 57-75us across r10-r12; MFMA changes the unit.
//  - agg: 8-acc bf16 gather, unchanged
//  - norm folded into gather table: xwb[i] = bf16(dinv[i] * (h@W)[i])

#define N_GRAPHS 256
#define HIDDEN 64
#define N_CLASSES 15
#define NB_SHIFT 9        // bucket = 512 consecutive nodes
#define MAXNB 256         // supports N <= 131072
#define EDGE_CHUNK 4096   // edges per block in cnt/place (16 per thread)

typedef __attribute__((ext_vector_type(8))) short bf16x8;
typedef __attribute__((ext_vector_type(4))) float f32x4;

__device__ __forceinline__ float bf2f(ushort u) {
    return __uint_as_float(((unsigned int)u) << 16);
}
__device__ __forceinline__ ushort f2bf(float f) {
    __hip_bfloat16 h = __float2bfloat16(f);  // RNE
    return *reinterpret_cast<ushort*>(&h);
}

// ---------------- per-(block,bucket) counts (LDS only) ----------------
__global__ __launch_bounds__(256) void cnt_kernel(const int* __restrict__ dst,
                                                  int* __restrict__ cnt, int E, int nblk) {
    __shared__ int lcnt[MAXNB];
    int blk = blockIdx.x;
    for (int i = threadIdx.x; i < MAXNB; i += 256) lcnt[i] = 0;
    __syncthreads();
    int base = blk * EDGE_CHUNK;
#pragma unroll
    for (int it = 0; it < EDGE_CHUNK / 256; ++it) {
        int e = base + it * 256 + threadIdx.x;
        if (e < E) atomicAdd(&lcnt[dst[e] >> NB_SHIFT], 1);
    }
    __syncthreads();
    for (int b = threadIdx.x; b < MAXNB; b += 256) cnt[b * nblk + blk] = lcnt[b];
}

// ---------------- bucket totals ----------------
__global__ __launch_bounds__(256) void btot_kernel(const int* __restrict__ cnt,
                                                   int* __restrict__ btot, int nblk) {
    int b = blockIdx.x;
    __shared__ int ls[256];
    int s = 0;
    for (int i = threadIdx.x; i < nblk; i += 256) s += cnt[b * nblk + i];
    ls[threadIdx.x] = s;
    __syncthreads();
    for (int off = 128; off > 0; off >>= 1) {
        if (threadIdx.x < off) ls[threadIdx.x] += ls[threadIdx.x + off];
        __syncthreads();
    }
    if (threadIdx.x == 0) btot[b] = ls[0];
}

// ---------------- tiny exclusive scan of bucket totals -> sbase[0..nb] ----------------
__global__ __launch_bounds__(256) void sscan_kernel(const int* __restrict__ btot,
                                                    int* __restrict__ sbase, int nb) {
    __shared__ int s[256];
    int t = threadIdx.x;
    s[t] = (t < nb) ? btot[t] : 0;
    __syncthreads();
    for (int off = 1; off < 256; off <<= 1) {
        int v = (t >= off) ? s[t - off] : 0;
        __syncthreads();
        s[t] += v;
        __syncthreads();
    }
    if (t < nb) sbase[t] = (t == 0) ? 0 : s[t - 1];
    if (t == 0) sbase[nb] = s[255];
}

// ---------------- cbase[b][blk] = sbase[b] + excl_scan_blk(cnt[b][:]) ----------------
__global__ __launch_bounds__(256) void cbase_kernel(const int* __restrict__ cnt,
                                                    const int* __restrict__ sbase,
                                                    int* __restrict__ cbase, int nblk) {
    int b = blockIdx.x;
    __shared__ int ls[256];
    int t = threadIdx.x;
    int chunk = (nblk + 255) / 256;
    int start = t * chunk;
    int end = start + chunk;
    if (end > nblk) end = nblk;
    int s = 0;
    for (int i = start; i < end; ++i) s += cnt[b * nblk + i];
    ls[t] = s;
    __syncthreads();
    for (int off = 1; off < 256; off <<= 1) {
        int v = (t >= off) ? ls[t - off] : 0;
        __syncthreads();
        ls[t] += v;
        __syncthreads();
    }
    int run = sbase[b] + ((t == 0) ? 0 : ls[t - 1]);
    for (int i = start; i < end; ++i) {
        cbase[b * nblk + i] = run;
        run += cnt[b * nblk + i];
    }
}

// ---------------- placement: LDS tickets, bucket-major staging ----------------
__global__ __launch_bounds__(256) void place_kernel(const int* __restrict__ src,
                                                    const int* __restrict__ dst,
                                                    const int* __restrict__ cbase,
                                                    int2* __restrict__ stage,
                                                    int E, int nblk, int nb) {
    __shared__ int lpos[MAXNB];
    int blk = blockIdx.x;
    for (int b = threadIdx.x; b < nb; b += 256) lpos[b] = cbase[b * nblk + blk];
    __syncthreads();
    int base = blk * EDGE_CHUNK;
#pragma unroll
    for (int it = 0; it < EDGE_CHUNK / 256; ++it) {
        int e = base + it * 256 + threadIdx.x;
        if (e < E) {
            int d = dst[e], s = src[e];
            int slot = atomicAdd(&lpos[d >> NB_SHIFT], 1);  // LDS ticket
            stage[slot] = make_int2(s, d);
        }
    }
}

// ---------------- finalize: per-bucket deg/rowptr/dinv + CSR col (all bucket-local) ----------------
__global__ __launch_bounds__(256) void finalize_kernel(const int2* __restrict__ stage,
                                                       const int* __restrict__ sbase,
                                                       int* __restrict__ rowptr,
                                                       float* __restrict__ dinv,
                                                       int* __restrict__ col, int n, int nb) {
    int b = blockIdx.x;
    int t = threadIdx.x;
    int node0 = b << NB_SHIFT;
    int lo = sbase[b], hi = sbase[b + 1];

    __shared__ int lcnt[1 << NB_SHIFT];
    __shared__ int lrow[1 << NB_SHIFT];
    __shared__ int ls[256];

    lcnt[t] = 0;
    lcnt[t + 256] = 0;
    __syncthreads();
    // pass 1: local degree histogram
    for (int e = lo + t; e < hi; e += 256) {
        atomicAdd(&lcnt[stage[e].y - node0], 1);
    }
    __syncthreads();
    // local exclusive scan over 512 counters (2 per thread)
    int c0 = lcnt[2 * t], c1 = lcnt[2 * t + 1];
    ls[t] = c0 + c1;
    __syncthreads();
    for (int off = 1; off < 256; off <<= 1) {
        int v = (t >= off) ? ls[t - off] : 0;
        __syncthreads();
        ls[t] += v;
        __syncthreads();
    }
    int bse = (t == 0) ? 0 : ls[t - 1];
    lrow[2 * t] = bse;
    lrow[2 * t + 1] = bse + c0;
    // rowptr / dinv
    int i0 = node0 + 2 * t;
    if (i0 < n) {
        rowptr[i0] = lo + bse;
        dinv[i0] = rsqrtf((float)(c0 + 1));  // +1 = self-loop
    }
    if (i0 + 1 < n) {
        rowptr[i0 + 1] = lo + bse + c0;
        dinv[i0 + 1] = rsqrtf((float)(c1 + 1));
    }
    if (b == nb - 1 && t == 0) rowptr[n] = hi;
    __syncthreads();
    // reset counters for ticketing
    lcnt[t] = 0;
    lcnt[t + 256] = 0;
    __syncthreads();
    // pass 2: place col within this bucket's contiguous window [lo, hi)
    for (int e = lo + t; e < hi; e += 256) {
        int2 sd = stage[e];
        int li = sd.y - node0;
        int k = atomicAdd(&lcnt[li], 1);  // LDS ticket
        col[lo + lrow[li] + k] = sd.x;
    }
}

// ---------------- MFMA GEMM: XWB(bf16) = dinv .* (X @ W) ----------------
// block = 256 threads (4 waves); each wave computes 16 rows x 64 cols; block = 64 rows.
// mfma_f32_16x16x32_bf16 layouts (guide-verified):
//   A[m=lane&15][k=8*(lane>>4)+j], B[k=8*(lane>>4)+j][n=lane&15],
//   D[row=4*(lane>>4)+j][col=lane&15].
// B: W -> LDS transposed bf16 wt[c][k], XOR swizzle byte^=((c&7)<<4) (else 16-way
// conflict on the 16-lane column read — r11 lesson). 16 (FIN=128) b128 reads -> VGPRs.
// A: per-lane global 16B load (bf16) or 2x16B + convert (fp32, layer 1). No LDS.
template <int FIN, typename TIN>
__global__ __launch_bounds__(256) void gemm_mfma_kernel(const TIN* __restrict__ X,
                                                        const float* __restrict__ W,
                                                        const float* __restrict__ dinv,
                                                        ushort* __restrict__ XWB, int n) {
    constexpr int NKC = FIN / 32;
    __shared__ __align__(16) ushort wt[64 * FIN];
    char* wtb = (char*)wt;
    for (int i = threadIdx.x; i < FIN * 64; i += 256) {
        int k = i >> 6, c = i & 63;            // W[i] = W[k][c], coalesced global read
        int byte = c * (FIN * 2) + k * 2;
        byte ^= ((c & 7) << 4);
        *(ushort*)(wtb + byte) = f2bf(W[i]);
    }
    __syncthreads();

    int lane = threadIdx.x & 63;
    int wv = threadIdx.x >> 6;
    int lo = lane & 15, hi = lane >> 4;

    // B-frags from swizzled LDS
    bf16x8 bfrag[NKC][4];
#pragma unroll
    for (int kc = 0; kc < NKC; ++kc) {
#pragma unroll
        for (int nc = 0; nc < 4; ++nc) {
            int c = nc * 16 + lo;
            int byte = c * (FIN * 2) + (kc * 32 + 8 * hi) * 2;
            byte ^= ((c & 7) << 4);
            bfrag[kc][nc] = *(const bf16x8*)(wtb + byte);
        }
    }

    int arow = blockIdx.x * 64 + wv * 16 + lo;  // row this lane's A-frag comes from
    f32x4 acc[4] = {{0.f, 0.f, 0.f, 0.f}, {0.f, 0.f, 0.f, 0.f},
                    {0.f, 0.f, 0.f, 0.f}, {0.f, 0.f, 0.f, 0.f}};
    const TIN* xr = X + (size_t)arow * FIN;
#pragma unroll
    for (int kc = 0; kc < NKC; ++kc) {
        int koff = kc * 32 + 8 * hi;
        bf16x8 af = {0, 0, 0, 0, 0, 0, 0, 0};
        if (arow < n) {
            if constexpr (sizeof(TIN) == 4) {
                float4 va = *reinterpret_cast<const float4*>((const float*)xr + koff);
                float4 vb = *reinterpret_cast<const float4*>((const float*)xr + koff + 4);
                af[0] = (short)f2bf(va.x); af[1] = (short)f2bf(va.y);
                af[2] = (short)f2bf(va.z); af[3] = (short)f2bf(va.w);
                af[4] = (short)f2bf(vb.x); af[5] = (short)f2bf(vb.y);
                af[6] = (short)f2bf(vb.z); af[7] = (short)f2bf(vb.w);
            } else {
                af = *reinterpret_cast<const bf16x8*>((const ushort*)xr + koff);
            }
        }
#pragma unroll
        for (int nc = 0; nc < 4; ++nc) {
            acc[nc] = __builtin_amdgcn_mfma_f32_16x16x32_bf16(af, bfrag[kc][nc], acc[nc], 0, 0, 0);
        }
    }

    // epilogue: D[row=4*hi+j][col=nc*16+lo]
    int orow0 = blockIdx.x * 64 + wv * 16 + 4 * hi;
#pragma unroll
    for (int j = 0; j < 4; ++j) {
        int orow = orow0 + j;
        if (orow < n) {
            float dv = dinv[orow];
            ushort* outr = XWB + (size_t)orow * 64 + lo;
#pragma unroll
            for (int nc = 0; nc < 4; ++nc) {
                outr[nc * 16] = f2bf(dv * acc[nc][j]);
            }
        }
    }
}

// ---------------- CSR aggregation: h = relu(dinv[i]*(xwb[i] + sum xwb[col]) + b), bf16 out ----------------
__global__ __launch_bounds__(256) void agg_csr_kernel(const ushort* __restrict__ XWB,
                                                      const int* __restrict__ rowptr,
                                                      const int* __restrict__ col,
                                                      const float* __restrict__ dinv,
                                                      const float* __restrict__ bias,
                                                      ushort* __restrict__ OUT, int n) {
    int lane = threadIdx.x & 63;
    int wid = (blockIdx.x * blockDim.x + threadIdx.x) >> 6;
    int nw = (gridDim.x * blockDim.x) >> 6;
    float b = bias[lane];
    for (int i = wid; i < n; i += nw) {
        float a0 = bf2f(XWB[(size_t)i * 64 + lane]);  // self-loop (pre-scaled)
        float a1 = 0.f, a2 = 0.f, a3 = 0.f, a4 = 0.f, a5 = 0.f, a6 = 0.f, a7 = 0.f;
        int p0 = __builtin_amdgcn_readfirstlane(rowptr[i]);
        int p1 = __builtin_amdgcn_readfirstlane(rowptr[i + 1]);
        int p = p0;
        for (; p + 8 <= p1; p += 8) {
            int c0 = col[p], c1 = col[p + 1], c2 = col[p + 2], c3 = col[p + 3];
            int c4 = col[p + 4], c5 = col[p + 5], c6 = col[p + 6], c7 = col[p + 7];
            a0 += bf2f(XWB[(size_t)c0 * 64 + lane]);
            a1 += bf2f(XWB[(size_t)c1 * 64 + lane]);
            a2 += bf2f(XWB[(size_t)c2 * 64 + lane]);
            a3 += bf2f(XWB[(size_t)c3 * 64 + lane]);
            a4 += bf2f(XWB[(size_t)c4 * 64 + lane]);
            a5 += bf2f(XWB[(size_t)c5 * 64 + lane]);
            a6 += bf2f(XWB[(size_t)c6 * 64 + lane]);
            a7 += bf2f(XWB[(size_t)c7 * 64 + lane]);
        }
        for (; p < p1; ++p) {
            a0 += bf2f(XWB[(size_t)col[p] * 64 + lane]);
        }
        float sum = ((a0 + a1) + (a2 + a3)) + ((a4 + a5) + (a6 + a7));
        float acc = dinv[i] * sum + b;
        OUT[(size_t)i * 64 + lane] = f2bf(fmaxf(acc, 0.f));
    }
}

// ---------------- mean pool (batch is sorted; H is bf16) ----------------
__global__ void pool_kernel(const ushort* __restrict__ H, const int* __restrict__ batch,
                            float* __restrict__ pooled, int n) {
    int g = blockIdx.x;
    int lo = 0, hi = n;
    while (lo < hi) { int mid = (lo + hi) >> 1; if (batch[mid] < g) lo = mid + 1; else hi = mid; }
    int start = lo;
    lo = 0; hi = n;
    while (lo < hi) { int mid = (lo + hi) >> 1; if (batch[mid] < g + 1) lo = mid + 1; else hi = mid; }
    int end = lo;

    int lane = threadIdx.x & 63;
    int w = threadIdx.x >> 6;
    __shared__ float part[4][64];
    float acc = 0.f;
    for (int i = start + w; i < end; i += 4) acc += bf2f(H[(size_t)i * 64 + lane]);
    part[w][lane] = acc;
    __syncthreads();
    if (w == 0) {
        float s = part[0][lane] + part[1][lane] + part[2][lane] + part[3][lane];
        float cnt = (float)(end - start);
        pooled[g * 64 + lane] = s / fmaxf(cnt, 1.0f);
    }
}

// ---------------- head ----------------
__global__ void head_kernel(const float* __restrict__ pooled, const float* __restrict__ fcw,
                            const float* __restrict__ fcb, float* __restrict__ out) {
    __shared__ float w[64 * N_CLASSES];
    __shared__ float bb[N_CLASSES];
    for (int i = threadIdx.x; i < 64 * N_CLASSES; i += blockDim.x) w[i] = fcw[i];
    if (threadIdx.x < N_CLASSES) bb[threadIdx.x] = fcb[threadIdx.x];
    __syncthreads();
    int g = threadIdx.x;  // 256 threads, one per graph
    float logits[N_CLASSES];
    float m = -1e30f;
    const float* pr = pooled + g * 64;
    for (int c = 0; c < N_CLASSES; ++c) {
        float acc = bb[c];
        for (int k = 0; k < 64; ++k) acc += pr[k] * w[k * N_CLASSES + c];
        logits[c] = acc;
        m = fmaxf(m, acc);
    }
    float se = 0.f;
    for (int c = 0; c < N_CLASSES; ++c) se += expf(logits[c] - m);
    float lse = m + logf(se);
    for (int c = 0; c < N_CLASSES; ++c) out[g * N_CLASSES + c] = logits[c] - lse;
}

extern "C" void kernel_launch(void* const* d_in, const int* in_sizes, int n_in,
                              void* d_out, int out_size, void* d_ws, size_t ws_size,
                              hipStream_t stream) {
    const float* x    = (const float*)d_in[0];
    const float* w1   = (const float*)d_in[1];
    const float* b1   = (const float*)d_in[2];
    const float* w2   = (const float*)d_in[3];
    const float* b2   = (const float*)d_in[4];
    const float* w3   = (const float*)d_in[5];
    const float* b3   = (const float*)d_in[6];
    const float* fcw  = (const float*)d_in[7];
    const float* fcb  = (const float*)d_in[8];
    const int*   ei   = (const int*)d_in[9];
    const int*   batch = (const int*)d_in[10];

    const int N = in_sizes[10];       // 100000
    const int E = in_sizes[9] / 2;    // 1600000
    const int* src = ei;
    const int* dst = ei + E;

    const int NBUCK = (N + (1 << NB_SHIFT) - 1) >> NB_SHIFT;   // 196
    const int NBLK = (E + EDGE_CHUNK - 1) / EDGE_CHUNK;        // 391

    char* ws = (char*)d_ws;
    size_t off = 0;
    auto alloc = [&](size_t bytes) -> void* {
        void* p = ws + off;
        off += (bytes + 255) & ~(size_t)255;
        return p;
    };
    int*    rowptr = (int*)alloc(((size_t)N + 1) * 4);
    int*    cnt    = (int*)alloc((size_t)MAXNB * NBLK * 4);
    int*    cbase  = (int*)alloc((size_t)MAXNB * NBLK * 4);
    int*    btot   = (int*)alloc(256 * 4);
    int*    sbase  = (int*)alloc(260 * 4);
    int2*   stage  = (int2*)alloc((size_t)E * 8);
    int*    col    = (int*)alloc((size_t)E * 4);
    float*  dinv   = (float*)alloc((size_t)N * 4);
    ushort* xwb    = (ushort*)alloc((size_t)N * 64 * 2);  // bf16 pre-scaled gather table
    ushort* hbuf   = (ushort*)alloc((size_t)N * 64 * 2);  // bf16 h
    float*  pooled = (float*)alloc((size_t)N_GRAPHS * 64 * 4);
    (void)ws_size;

    const int GB = 2048;

    cnt_kernel<<<NBLK, 256, 0, stream>>>(dst, cnt, E, NBLK);
    btot_kernel<<<NBUCK, 256, 0, stream>>>(cnt, btot, NBLK);
    sscan_kernel<<<1, 256, 0, stream>>>(btot, sbase, NBUCK);
    cbase_kernel<<<NBUCK, 256, 0, stream>>>(cnt, sbase, cbase, NBLK);
    place_kernel<<<NBLK, 256, 0, stream>>>(src, dst, cbase, stage, E, NBLK, NBUCK);
    finalize_kernel<<<NBUCK, 256, 0, stream>>>(stage, sbase, rowptr, dinv, col, N, NBUCK);

    int gtiles = (N + 63) / 64;  // 1563 blocks, 64 rows each

    // layer 1
    gemm_mfma_kernel<128, float><<<gtiles, 256, 0, stream>>>(x, w1, dinv, xwb, N);
    agg_csr_kernel<<<GB, 256, 0, stream>>>(xwb, rowptr, col, dinv, b1, hbuf, N);
    // layer 2
    gemm_mfma_kernel<64, ushort><<<gtiles, 256, 0, stream>>>(hbuf, w2, dinv, xwb, N);
    agg_csr_kernel<<<GB, 256, 0, stream>>>(xwb, rowptr, col, dinv, b2, hbuf, N);
    // layer 3
    gemm_mfma_kernel<64, ushort><<<gtiles, 256, 0, stream>>>(hbuf, w3, dinv, xwb, N);
    agg_csr_kernel<<<GB, 256, 0, stream>>>(xwb, rowptr, col, dinv, b3, hbuf, N);

    pool_kernel<<<N_GRAPHS, 256, 0, stream>>>(hbuf, batch, pooled, N);
    head_kernel<<<1, 256, 0, stream>>>(pooled, fcw, fcb, (float*)d_out);
}

// Round 14
// 265.673 us; speedup vs baseline: 1.3489x; 1.0384x over previous
//
#include <hip/hip_runtime.h>
#include <hip/hip_bf16.h>

// GCN: 3x GCNConv(relu) + mean-pool + linear + log_softmax
// N=100000 nodes, E=1600000 edges, F=128 -> 64 -> 64 -> 64, 256 graphs, 15 classes.
//
// Round 14 structure (= r13 + paired-row aggregation):
//  - build: zero global atomics (cnt/btot/sscan/cbase/place/finalize), r10-measured
//  - gemm: mfma_f32_16x16x32_bf16 (r13-measured: out of top-5)
//  - agg: 2 rows per wave, 32 lanes/row, 2 feats/lane (uint = 2xbf16).
//    One wave instruction = 256B gather payload (2 edges' worth) vs 128B before.
//    r13 agg counters (47.5us, VALU 20%, L3 1.9 TB/s, 0 conflicts) => issue-bound.
//  - norm folded into gather table: xwb[i] = bf16(dinv[i] * (h@W)[i])

#define N_GRAPHS 256
#define HIDDEN 64
#define N_CLASSES 15
#define NB_SHIFT 9        // bucket = 512 consecutive nodes
#define MAXNB 256         // supports N <= 131072
#define EDGE_CHUNK 4096   // edges per block in cnt/place (16 per thread)

typedef __attribute__((ext_vector_type(8))) short bf16x8;
typedef __attribute__((ext_vector_type(4))) float f32x4;

__device__ __forceinline__ float bf2f(ushort u) {
    return __uint_as_float(((unsigned int)u) << 16);
}
__device__ __forceinline__ ushort f2bf(float f) {
    __hip_bfloat16 h = __float2bfloat16(f);  // RNE
    return *reinterpret_cast<ushort*>(&h);
}

// ---------------- per-(block,bucket) counts (LDS only) ----------------
__global__ __launch_bounds__(256) void cnt_kernel(const int* __restrict__ dst,
                                                  int* __restrict__ cnt, int E, int nblk) {
    __shared__ int lcnt[MAXNB];
    int blk = blockIdx.x;
    for (int i = threadIdx.x; i < MAXNB; i += 256) lcnt[i] = 0;
    __syncthreads();
    int base = blk * EDGE_CHUNK;
#pragma unroll
    for (int it = 0; it < EDGE_CHUNK / 256; ++it) {
        int e = base + it * 256 + threadIdx.x;
        if (e < E) atomicAdd(&lcnt[dst[e] >> NB_SHIFT], 1);
    }
    __syncthreads();
    for (int b = threadIdx.x; b < MAXNB; b += 256) cnt[b * nblk + blk] = lcnt[b];
}

// ---------------- bucket totals ----------------
__global__ __launch_bounds__(256) void btot_kernel(const int* __restrict__ cnt,
                                                   int* __restrict__ btot, int nblk) {
    int b = blockIdx.x;
    __shared__ int ls[256];
    int s = 0;
    for (int i = threadIdx.x; i < nblk; i += 256) s += cnt[b * nblk + i];
    ls[threadIdx.x] = s;
    __syncthreads();
    for (int off = 128; off > 0; off >>= 1) {
        if (threadIdx.x < off) ls[threadIdx.x] += ls[threadIdx.x + off];
        __syncthreads();
    }
    if (threadIdx.x == 0) btot[b] = ls[0];
}

// ---------------- tiny exclusive scan of bucket totals -> sbase[0..nb] ----------------
__global__ __launch_bounds__(256) void sscan_kernel(const int* __restrict__ btot,
                                                    int* __restrict__ sbase, int nb) {
    __shared__ int s[256];
    int t = threadIdx.x;
    s[t] = (t < nb) ? btot[t] : 0;
    __syncthreads();
    for (int off = 1; off < 256; off <<= 1) {
        int v = (t >= off) ? s[t - off] : 0;
        __syncthreads();
        s[t] += v;
        __syncthreads();
    }
    if (t < nb) sbase[t] = (t == 0) ? 0 : s[t - 1];
    if (t == 0) sbase[nb] = s[255];
}

// ---------------- cbase[b][blk] = sbase[b] + excl_scan_blk(cnt[b][:]) ----------------
__global__ __launch_bounds__(256) void cbase_kernel(const int* __restrict__ cnt,
                                                    const int* __restrict__ sbase,
                                                    int* __restrict__ cbase, int nblk) {
    int b = blockIdx.x;
    __shared__ int ls[256];
    int t = threadIdx.x;
    int chunk = (nblk + 255) / 256;
    int start = t * chunk;
    int end = start + chunk;
    if (end > nblk) end = nblk;
    int s = 0;
    for (int i = start; i < end; ++i) s += cnt[b * nblk + i];
    ls[t] = s;
    __syncthreads();
    for (int off = 1; off < 256; off <<= 1) {
        int v = (t >= off) ? ls[t - off] : 0;
        __syncthreads();
        ls[t] += v;
        __syncthreads();
    }
    int run = sbase[b] + ((t == 0) ? 0 : ls[t - 1]);
    for (int i = start; i < end; ++i) {
        cbase[b * nblk + i] = run;
        run += cnt[b * nblk + i];
    }
}

// ---------------- placement: LDS tickets, bucket-major staging ----------------
__global__ __launch_bounds__(256) void place_kernel(const int* __restrict__ src,
                                                    const int* __restrict__ dst,
                                                    const int* __restrict__ cbase,
                                                    int2* __restrict__ stage,
                                                    int E, int nblk, int nb) {
    __shared__ int lpos[MAXNB];
    int blk = blockIdx.x;
    for (int b = threadIdx.x; b < nb; b += 256) lpos[b] = cbase[b * nblk + blk];
    __syncthreads();
    int base = blk * EDGE_CHUNK;
#pragma unroll
    for (int it = 0; it < EDGE_CHUNK / 256; ++it) {
        int e = base + it * 256 + threadIdx.x;
        if (e < E) {
            int d = dst[e], s = src[e];
            int slot = atomicAdd(&lpos[d >> NB_SHIFT], 1);  // LDS ticket
            stage[slot] = make_int2(s, d);
        }
    }
}

// ---------------- finalize: per-bucket deg/rowptr/dinv + CSR col (all bucket-local) ----------------
__global__ __launch_bounds__(256) void finalize_kernel(const int2* __restrict__ stage,
                                                       const int* __restrict__ sbase,
                                                       int* __restrict__ rowptr,
                                                       float* __restrict__ dinv,
                                                       int* __restrict__ col, int n, int nb) {
    int b = blockIdx.x;
    int t = threadIdx.x;
    int node0 = b << NB_SHIFT;
    int lo = sbase[b], hi = sbase[b + 1];

    __shared__ int lcnt[1 << NB_SHIFT];
    __shared__ int lrow[1 << NB_SHIFT];
    __shared__ int ls[256];

    lcnt[t] = 0;
    lcnt[t + 256] = 0;
    __syncthreads();
    // pass 1: local degree histogram
    for (int e = lo + t; e < hi; e += 256) {
        atomicAdd(&lcnt[stage[e].y - node0], 1);
    }
    __syncthreads();
    // local exclusive scan over 512 counters (2 per thread)
    int c0 = lcnt[2 * t], c1 = lcnt[2 * t + 1];
    ls[t] = c0 + c1;
    __syncthreads();
    for (int off = 1; off < 256; off <<= 1) {
        int v = (t >= off) ? ls[t - off] : 0;
        __syncthreads();
        ls[t] += v;
        __syncthreads();
    }
    int bse = (t == 0) ? 0 : ls[t - 1];
    lrow[2 * t] = bse;
    lrow[2 * t + 1] = bse + c0;
    // rowptr / dinv
    int i0 = node0 + 2 * t;
    if (i0 < n) {
        rowptr[i0] = lo + bse;
        dinv[i0] = rsqrtf((float)(c0 + 1));  // +1 = self-loop
    }
    if (i0 + 1 < n) {
        rowptr[i0 + 1] = lo + bse + c0;
        dinv[i0 + 1] = rsqrtf((float)(c1 + 1));
    }
    if (b == nb - 1 && t == 0) rowptr[n] = hi;
    __syncthreads();
    // reset counters for ticketing
    lcnt[t] = 0;
    lcnt[t + 256] = 0;
    __syncthreads();
    // pass 2: place col within this bucket's contiguous window [lo, hi)
    for (int e = lo + t; e < hi; e += 256) {
        int2 sd = stage[e];
        int li = sd.y - node0;
        int k = atomicAdd(&lcnt[li], 1);  // LDS ticket
        col[lo + lrow[li] + k] = sd.x;
    }
}

// ---------------- MFMA GEMM: XWB(bf16) = dinv .* (X @ W) ----------------
// block = 256 threads (4 waves); each wave computes 16 rows x 64 cols; block = 64 rows.
template <int FIN, typename TIN>
__global__ __launch_bounds__(256) void gemm_mfma_kernel(const TIN* __restrict__ X,
                                                        const float* __restrict__ W,
                                                        const float* __restrict__ dinv,
                                                        ushort* __restrict__ XWB, int n) {
    constexpr int NKC = FIN / 32;
    __shared__ __align__(16) ushort wt[64 * FIN];
    char* wtb = (char*)wt;
    for (int i = threadIdx.x; i < FIN * 64; i += 256) {
        int k = i >> 6, c = i & 63;            // W[i] = W[k][c], coalesced global read
        int byte = c * (FIN * 2) + k * 2;
        byte ^= ((c & 7) << 4);
        *(ushort*)(wtb + byte) = f2bf(W[i]);
    }
    __syncthreads();

    int lane = threadIdx.x & 63;
    int wv = threadIdx.x >> 6;
    int lo = lane & 15, hi = lane >> 4;

    // B-frags from swizzled LDS
    bf16x8 bfrag[NKC][4];
#pragma unroll
    for (int kc = 0; kc < NKC; ++kc) {
#pragma unroll
        for (int nc = 0; nc < 4; ++nc) {
            int c = nc * 16 + lo;
            int byte = c * (FIN * 2) + (kc * 32 + 8 * hi) * 2;
            byte ^= ((c & 7) << 4);
            bfrag[kc][nc] = *(const bf16x8*)(wtb + byte);
        }
    }

    int arow = blockIdx.x * 64 + wv * 16 + lo;  // row this lane's A-frag comes from
    f32x4 acc[4] = {{0.f, 0.f, 0.f, 0.f}, {0.f, 0.f, 0.f, 0.f},
                    {0.f, 0.f, 0.f, 0.f}, {0.f, 0.f, 0.f, 0.f}};
    const TIN* xr = X + (size_t)arow * FIN;
#pragma unroll
    for (int kc = 0; kc < NKC; ++kc) {
        int koff = kc * 32 + 8 * hi;
        bf16x8 af = {0, 0, 0, 0, 0, 0, 0, 0};
        if (arow < n) {
            if constexpr (sizeof(TIN) == 4) {
                float4 va = *reinterpret_cast<const float4*>((const float*)xr + koff);
                float4 vb = *reinterpret_cast<const float4*>((const float*)xr + koff + 4);
                af[0] = (short)f2bf(va.x); af[1] = (short)f2bf(va.y);
                af[2] = (short)f2bf(va.z); af[3] = (short)f2bf(va.w);
                af[4] = (short)f2bf(vb.x); af[5] = (short)f2bf(vb.y);
                af[6] = (short)f2bf(vb.z); af[7] = (short)f2bf(vb.w);
            } else {
                af = *reinterpret_cast<const bf16x8*>((const ushort*)xr + koff);
            }
        }
#pragma unroll
        for (int nc = 0; nc < 4; ++nc) {
            acc[nc] = __builtin_amdgcn_mfma_f32_16x16x32_bf16(af, bfrag[kc][nc], acc[nc], 0, 0, 0);
        }
    }

    // epilogue: D[row=4*hi+j][col=nc*16+lo]
    int orow0 = blockIdx.x * 64 + wv * 16 + 4 * hi;
#pragma unroll
    for (int j = 0; j < 4; ++j) {
        int orow = orow0 + j;
        if (orow < n) {
            float dv = dinv[orow];
            ushort* outr = XWB + (size_t)orow * 64 + lo;
#pragma unroll
            for (int nc = 0; nc < 4; ++nc) {
                outr[nc * 16] = f2bf(dv * acc[nc][j]);
            }
        }
    }
}

// ---------------- paired-row CSR aggregation ----------------
// 2 rows per wave: half = lane>>5 picks the row, 32 lanes x 2 feats (uint = 2xbf16).
// One wave gather instruction = 256B payload (one edge-gather for EACH of 2 rows).
__global__ __launch_bounds__(256) void agg_pair_kernel(const ushort* __restrict__ XWB,
                                                       const int* __restrict__ rowptr,
                                                       const int* __restrict__ col,
                                                       const float* __restrict__ dinv,
                                                       const float* __restrict__ bias,
                                                       ushort* __restrict__ OUT, int n) {
    int lane = threadIdx.x & 63;
    int half = lane >> 5;
    int sl = lane & 31;
    int wid = (blockIdx.x * blockDim.x + threadIdx.x) >> 6;
    int nw = (gridDim.x * blockDim.x) >> 6;
    float b0 = bias[sl * 2];
    float b1 = bias[sl * 2 + 1];
    int npairs = (n + 1) >> 1;
    for (int pr = wid; pr < npairs; pr += nw) {
        int i = pr * 2 + half;
        bool valid = i < n;
        int p = 0, pend = 0;
        float a0x = 0.f, a0y = 0.f;
        if (valid) {
            p = rowptr[i];
            pend = rowptr[i + 1];
            unsigned int v = *reinterpret_cast<const unsigned int*>(XWB + (size_t)i * 64 + sl * 2);
            a0x = bf2f((ushort)(v & 0xffff));  // self-loop (pre-scaled)
            a0y = bf2f((ushort)(v >> 16));
        }
        float a1x = 0.f, a1y = 0.f, a2x = 0.f, a2y = 0.f, a3x = 0.f, a3y = 0.f;
        float a4x = 0.f, a4y = 0.f, a5x = 0.f, a5y = 0.f, a6x = 0.f, a6y = 0.f;
        float a7x = 0.f, a7y = 0.f;
        for (; p + 8 <= pend; p += 8) {
            int c0 = col[p], c1 = col[p + 1], c2 = col[p + 2], c3 = col[p + 3];
            int c4 = col[p + 4], c5 = col[p + 5], c6 = col[p + 6], c7 = col[p + 7];
            unsigned int v0 = *reinterpret_cast<const unsigned int*>(XWB + (size_t)c0 * 64 + sl * 2);
            unsigned int v1 = *reinterpret_cast<const unsigned int*>(XWB + (size_t)c1 * 64 + sl * 2);
            unsigned int v2 = *reinterpret_cast<const unsigned int*>(XWB + (size_t)c2 * 64 + sl * 2);
            unsigned int v3 = *reinterpret_cast<const unsigned int*>(XWB + (size_t)c3 * 64 + sl * 2);
            unsigned int v4 = *reinterpret_cast<const unsigned int*>(XWB + (size_t)c4 * 64 + sl * 2);
            unsigned int v5 = *reinterpret_cast<const unsigned int*>(XWB + (size_t)c5 * 64 + sl * 2);
            unsigned int v6 = *reinterpret_cast<const unsigned int*>(XWB + (size_t)c6 * 64 + sl * 2);
            unsigned int v7 = *reinterpret_cast<const unsigned int*>(XWB + (size_t)c7 * 64 + sl * 2);
            a0x += bf2f((ushort)(v0 & 0xffff)); a0y += bf2f((ushort)(v0 >> 16));
            a1x += bf2f((ushort)(v1 & 0xffff)); a1y += bf2f((ushort)(v1 >> 16));
            a2x += bf2f((ushort)(v2 & 0xffff)); a2y += bf2f((ushort)(v2 >> 16));
            a3x += bf2f((ushort)(v3 & 0xffff)); a3y += bf2f((ushort)(v3 >> 16));
            a4x += bf2f((ushort)(v4 & 0xffff)); a4y += bf2f((ushort)(v4 >> 16));
            a5x += bf2f((ushort)(v5 & 0xffff)); a5y += bf2f((ushort)(v5 >> 16));
            a6x += bf2f((ushort)(v6 & 0xffff)); a6y += bf2f((ushort)(v6 >> 16));
            a7x += bf2f((ushort)(v7 & 0xffff)); a7y += bf2f((ushort)(v7 >> 16));
        }
        for (; p < pend; ++p) {
            unsigned int v = *reinterpret_cast<const unsigned int*>(XWB + (size_t)col[p] * 64 + sl * 2);
            a0x += bf2f((ushort)(v & 0xffff));
            a0y += bf2f((ushort)(v >> 16));
        }
        if (valid) {
            float sx = ((a0x + a1x) + (a2x + a3x)) + ((a4x + a5x) + (a6x + a7x));
            float sy = ((a0y + a1y) + (a2y + a3y)) + ((a4y + a5y) + (a6y + a7y));
            float di = dinv[i];
            unsigned int o = (unsigned int)f2bf(fmaxf(di * sx + b0, 0.f))
                           | ((unsigned int)f2bf(fmaxf(di * sy + b1, 0.f)) << 16);
            *reinterpret_cast<unsigned int*>(OUT + (size_t)i * 64 + sl * 2) = o;
        }
    }
}

// ---------------- mean pool (batch is sorted; H is bf16) ----------------
__global__ void pool_kernel(const ushort* __restrict__ H, const int* __restrict__ batch,
                            float* __restrict__ pooled, int n) {
    int g = blockIdx.x;
    int lo = 0, hi = n;
    while (lo < hi) { int mid = (lo + hi) >> 1; if (batch[mid] < g) lo = mid + 1; else hi = mid; }
    int start = lo;
    lo = 0; hi = n;
    while (lo < hi) { int mid = (lo + hi) >> 1; if (batch[mid] < g + 1) lo = mid + 1; else hi = mid; }
    int end = lo;

    int lane = threadIdx.x & 63;
    int w = threadIdx.x >> 6;
    __shared__ float part[4][64];
    float acc = 0.f;
    for (int i = start + w; i < end; i += 4) acc += bf2f(H[(size_t)i * 64 + lane]);
    part[w][lane] = acc;
    __syncthreads();
    if (w == 0) {
        float s = part[0][lane] + part[1][lane] + part[2][lane] + part[3][lane];
        float cnt = (float)(end - start);
        pooled[g * 64 + lane] = s / fmaxf(cnt, 1.0f);
    }
}

// ---------------- head ----------------
__global__ void head_kernel(const float* __restrict__ pooled, const float* __restrict__ fcw,
                            const float* __restrict__ fcb, float* __restrict__ out) {
    __shared__ float w[64 * N_CLASSES];
    __shared__ float bb[N_CLASSES];
    for (int i = threadIdx.x; i < 64 * N_CLASSES; i += blockDim.x) w[i] = fcw[i];
    if (threadIdx.x < N_CLASSES) bb[threadIdx.x] = fcb[threadIdx.x];
    __syncthreads();
    int g = threadIdx.x;  // 256 threads, one per graph
    float logits[N_CLASSES];
    float m = -1e30f;
    const float* pr = pooled + g * 64;
    for (int c = 0; c < N_CLASSES; ++c) {
        float acc = bb[c];
        for (int k = 0; k < 64; ++k) acc += pr[k] * w[k * N_CLASSES + c];
        logits[c] = acc;
        m = fmaxf(m, acc);
    }
    float se = 0.f;
    for (int c = 0; c < N_CLASSES; ++c) se += expf(logits[c] - m);
    float lse = m + logf(se);
    for (int c = 0; c < N_CLASSES; ++c) out[g * N_CLASSES + c] = logits[c] - lse;
}

extern "C" void kernel_launch(void* const* d_in, const int* in_sizes, int n_in,
                              void* d_out, int out_size, void* d_ws, size_t ws_size,
                              hipStream_t stream) {
    const float* x    = (const float*)d_in[0];
    const float* w1   = (const float*)d_in[1];
    const float* b1   = (const float*)d_in[2];
    const float* w2   = (const float*)d_in[3];
    const float* b2   = (const float*)d_in[4];
    const float* w3   = (const float*)d_in[5];
    const float* b3   = (const float*)d_in[6];
    const float* fcw  = (const float*)d_in[7];
    const float* fcb  = (const float*)d_in[8];
    const int*   ei   = (const int*)d_in[9];
    const int*   batch = (const int*)d_in[10];

    const int N = in_sizes[10];       // 100000
    const int E = in_sizes[9] / 2;    // 1600000
    const int* src = ei;
    const int* dst = ei + E;

    const int NBUCK = (N + (1 << NB_SHIFT) - 1) >> NB_SHIFT;   // 196
    const int NBLK = (E + EDGE_CHUNK - 1) / EDGE_CHUNK;        // 391

    char* ws = (char*)d_ws;
    size_t off = 0;
    auto alloc = [&](size_t bytes) -> void* {
        void* p = ws + off;
        off += (bytes + 255) & ~(size_t)255;
        return p;
    };
    int*    rowptr = (int*)alloc(((size_t)N + 1) * 4);
    int*    cnt    = (int*)alloc((size_t)MAXNB * NBLK * 4);
    int*    cbase  = (int*)alloc((size_t)MAXNB * NBLK * 4);
    int*    btot   = (int*)alloc(256 * 4);
    int*    sbase  = (int*)alloc(260 * 4);
    int2*   stage  = (int2*)alloc((size_t)E * 8);
    int*    col    = (int*)alloc((size_t)E * 4);
    float*  dinv   = (float*)alloc((size_t)N * 4);
    ushort* xwb    = (ushort*)alloc((size_t)N * 64 * 2);  // bf16 pre-scaled gather table
    ushort* hbuf   = (ushort*)alloc((size_t)N * 64 * 2);  // bf16 h
    float*  pooled = (float*)alloc((size_t)N_GRAPHS * 64 * 4);
    (void)ws_size;

    const int GB = 2048;

    cnt_kernel<<<NBLK, 256, 0, stream>>>(dst, cnt, E, NBLK);
    btot_kernel<<<NBUCK, 256, 0, stream>>>(cnt, btot, NBLK);
    sscan_kernel<<<1, 256, 0, stream>>>(btot, sbase, NBUCK);
    cbase_kernel<<<NBUCK, 256, 0, stream>>>(cnt, sbase, cbase, NBLK);
    place_kernel<<<NBLK, 256, 0, stream>>>(src, dst, cbase, stage, E, NBLK, NBUCK);
    finalize_kernel<<<NBUCK, 256, 0, stream>>>(stage, sbase, rowptr, dinv, col, N, NBUCK);

    int gtiles = (N + 63) / 64;  // 1563 blocks, 64 rows each

    // layer 1
    gemm_mfma_kernel<128, float><<<gtiles, 256, 0, stream>>>(x, w1, dinv, xwb, N);
    agg_pair_kernel<<<GB, 256, 0, stream>>>(xwb, rowptr, col, dinv, b1, hbuf, N);
    // layer 2
    gemm_mfma_kernel<64, ushort><<<gtiles, 256, 0, stream>>>(hbuf, w2, dinv, xwb, N);
    agg_pair_kernel<<<GB, 256, 0, stream>>>(xwb, rowptr, col, dinv, b2, hbuf, N);
    // layer 3
    gemm_mfma_kernel<64, ushort><<<gtiles, 256, 0, stream>>>(hbuf, w3, dinv, xwb, N);
    agg_pair_kernel<<<GB, 256, 0, stream>>>(xwb, rowptr, col, dinv, b3, hbuf, N);

    pool_kernel<<<N_GRAPHS, 256, 0, stream>>>(hbuf, batch, pooled, N);
    head_kernel<<<1, 256, 0, stream>>>(pooled, fcw, fcb, (float*)d_out);
}

// Round 15
// 217.430 us; speedup vs baseline: 1.6482x; 1.2219x over previous
//
#include <hip/hip_runtime.h>
#include <hip/hip_bf16.h>

// GCN: 3x GCNConv(relu) + mean-pool + linear + log_softmax
// N=100000 nodes, E=1600000 edges, F=128 -> 64 -> 64 -> 64, 256 graphs, 15 classes.
//
// Round 15 structure (= r14 + fp8 gather table + packed stage):
//  - gather table xwb in FP8 e4m3 (OCP), pre-scaled: xwb[i] = fp8(dinv[i]*(h@W)[i]).
//    r13/r14 showed agg bound by L2-miss line traffic (~84MB = 8 XCD x table);
//    fp8 halves the table (6.4MB) and makes a row = 64B = ONE cache line.
//  - agg: 4 rows/wave, 16 lanes/row, 4 feats/lane (uint of 4xfp8), fp32 accum,
//    bf16 h output (gemm A stays bf16).
//  - stage packed to 4B: src | (dst&511)<<23  (src 17b, local-dst 9b)
//  - build: zero global atomics; gemm: mfma_f32_16x16x32_bf16

#define N_GRAPHS 256
#define HIDDEN 64
#define N_CLASSES 15
#define NB_SHIFT 9        // bucket = 512 consecutive nodes
#define MAXNB 256         // supports N <= 131072
#define EDGE_CHUNK 4096   // edges per block in cnt/place (16 per thread)

typedef __attribute__((ext_vector_type(8))) short bf16x8;
typedef __attribute__((ext_vector_type(4))) float f32x4;
typedef __attribute__((ext_vector_type(2))) float f32x2;

__device__ __forceinline__ float bf2f(ushort u) {
    return __uint_as_float(((unsigned int)u) << 16);
}
__device__ __forceinline__ ushort f2bf(float f) {
    __hip_bfloat16 h = __float2bfloat16(f);  // RNE
    return *reinterpret_cast<ushort*>(&h);
}
__device__ __forceinline__ unsigned char f2fp8(float f) {
    int p = __builtin_amdgcn_cvt_pk_fp8_f32(f, f, 0, false);
    return (unsigned char)(p & 0xff);
}

// ---------------- per-(block,bucket) counts (LDS only) ----------------
__global__ __launch_bounds__(256) void cnt_kernel(const int* __restrict__ dst,
                                                  int* __restrict__ cnt, int E, int nblk) {
    __shared__ int lcnt[MAXNB];
    int blk = blockIdx.x;
    for (int i = threadIdx.x; i < MAXNB; i += 256) lcnt[i] = 0;
    __syncthreads();
    int base = blk * EDGE_CHUNK;
#pragma unroll
    for (int it = 0; it < EDGE_CHUNK / 256; ++it) {
        int e = base + it * 256 + threadIdx.x;
        if (e < E) atomicAdd(&lcnt[dst[e] >> NB_SHIFT], 1);
    }
    __syncthreads();
    for (int b = threadIdx.x; b < MAXNB; b += 256) cnt[b * nblk + blk] = lcnt[b];
}

// ---------------- bucket totals ----------------
__global__ __launch_bounds__(256) void btot_kernel(const int* __restrict__ cnt,
                                                   int* __restrict__ btot, int nblk) {
    int b = blockIdx.x;
    __shared__ int ls[256];
    int s = 0;
    for (int i = threadIdx.x; i < nblk; i += 256) s += cnt[b * nblk + i];
    ls[threadIdx.x] = s;
    __syncthreads();
    for (int off = 128; off > 0; off >>= 1) {
        if (threadIdx.x < off) ls[threadIdx.x] += ls[threadIdx.x + off];
        __syncthreads();
    }
    if (threadIdx.x == 0) btot[b] = ls[0];
}

// ---------------- tiny exclusive scan of bucket totals -> sbase[0..nb] ----------------
__global__ __launch_bounds__(256) void sscan_kernel(const int* __restrict__ btot,
                                                    int* __restrict__ sbase, int nb) {
    __shared__ int s[256];
    int t = threadIdx.x;
    s[t] = (t < nb) ? btot[t] : 0;
    __syncthreads();
    for (int off = 1; off < 256; off <<= 1) {
        int v = (t >= off) ? s[t - off] : 0;
        __syncthreads();
        s[t] += v;
        __syncthreads();
    }
    if (t < nb) sbase[t] = (t == 0) ? 0 : s[t - 1];
    if (t == 0) sbase[nb] = s[255];
}

// ---------------- cbase[b][blk] = sbase[b] + excl_scan_blk(cnt[b][:]) ----------------
__global__ __launch_bounds__(256) void cbase_kernel(const int* __restrict__ cnt,
                                                    const int* __restrict__ sbase,
                                                    int* __restrict__ cbase, int nblk) {
    int b = blockIdx.x;
    __shared__ int ls[256];
    int t = threadIdx.x;
    int chunk = (nblk + 255) / 256;
    int start = t * chunk;
    int end = start + chunk;
    if (end > nblk) end = nblk;
    int s = 0;
    for (int i = start; i < end; ++i) s += cnt[b * nblk + i];
    ls[t] = s;
    __syncthreads();
    for (int off = 1; off < 256; off <<= 1) {
        int v = (t >= off) ? ls[t - off] : 0;
        __syncthreads();
        ls[t] += v;
        __syncthreads();
    }
    int run = sbase[b] + ((t == 0) ? 0 : ls[t - 1]);
    for (int i = start; i < end; ++i) {
        cbase[b * nblk + i] = run;
        run += cnt[b * nblk + i];
    }
}

// ---------------- placement: LDS tickets, bucket-major packed staging ----------------
__global__ __launch_bounds__(256) void place_kernel(const int* __restrict__ src,
                                                    const int* __restrict__ dst,
                                                    const int* __restrict__ cbase,
                                                    unsigned int* __restrict__ stage,
                                                    int E, int nblk, int nb) {
    __shared__ int lpos[MAXNB];
    int blk = blockIdx.x;
    for (int b = threadIdx.x; b < nb; b += 256) lpos[b] = cbase[b * nblk + blk];
    __syncthreads();
    int base = blk * EDGE_CHUNK;
#pragma unroll
    for (int it = 0; it < EDGE_CHUNK / 256; ++it) {
        int e = base + it * 256 + threadIdx.x;
        if (e < E) {
            int d = dst[e], s = src[e];
            int slot = atomicAdd(&lpos[d >> NB_SHIFT], 1);  // LDS ticket
            stage[slot] = (unsigned int)s | ((unsigned int)(d & ((1 << NB_SHIFT) - 1)) << 23);
        }
    }
}

// ---------------- finalize: per-bucket deg/rowptr/dinv + CSR col (all bucket-local) ----------------
__global__ __launch_bounds__(256) void finalize_kernel(const unsigned int* __restrict__ stage,
                                                       const int* __restrict__ sbase,
                                                       int* __restrict__ rowptr,
                                                       float* __restrict__ dinv,
                                                       int* __restrict__ col, int n, int nb) {
    int b = blockIdx.x;
    int t = threadIdx.x;
    int node0 = b << NB_SHIFT;
    int lo = sbase[b], hi = sbase[b + 1];

    __shared__ int lcnt[1 << NB_SHIFT];
    __shared__ int lrow[1 << NB_SHIFT];
    __shared__ int ls[256];

    lcnt[t] = 0;
    lcnt[t + 256] = 0;
    __syncthreads();
    // pass 1: local degree histogram
    for (int e = lo + t; e < hi; e += 256) {
        atomicAdd(&lcnt[stage[e] >> 23], 1);
    }
    __syncthreads();
    // local exclusive scan over 512 counters (2 per thread)
    int c0 = lcnt[2 * t], c1 = lcnt[2 * t + 1];
    ls[t] = c0 + c1;
    __syncthreads();
    for (int off = 1; off < 256; off <<= 1) {
        int v = (t >= off) ? ls[t - off] : 0;
        __syncthreads();
        ls[t] += v;
        __syncthreads();
    }
    int bse = (t == 0) ? 0 : ls[t - 1];
    lrow[2 * t] = bse;
    lrow[2 * t + 1] = bse + c0;
    // rowptr / dinv
    int i0 = node0 + 2 * t;
    if (i0 < n) {
        rowptr[i0] = lo + bse;
        dinv[i0] = rsqrtf((float)(c0 + 1));  // +1 = self-loop
    }
    if (i0 + 1 < n) {
        rowptr[i0 + 1] = lo + bse + c0;
        dinv[i0 + 1] = rsqrtf((float)(c1 + 1));
    }
    if (b == nb - 1 && t == 0) rowptr[n] = hi;
    __syncthreads();
    // reset counters for ticketing
    lcnt[t] = 0;
    lcnt[t + 256] = 0;
    __syncthreads();
    // pass 2: place col within this bucket's contiguous window [lo, hi)
    for (int e = lo + t; e < hi; e += 256) {
        unsigned int v = stage[e];
        int li = v >> 23;
        int k = atomicAdd(&lcnt[li], 1);  // LDS ticket
        col[lo + lrow[li] + k] = (int)(v & 0x7fffff);
    }
}

// ---------------- MFMA GEMM: XWB(fp8) = dinv .* (X @ W) ----------------
// block = 256 threads (4 waves); each wave computes 16 rows x 64 cols; block = 64 rows.
template <int FIN, typename TIN>
__global__ __launch_bounds__(256) void gemm_mfma_kernel(const TIN* __restrict__ X,
                                                        const float* __restrict__ W,
                                                        const float* __restrict__ dinv,
                                                        unsigned char* __restrict__ XWB, int n) {
    constexpr int NKC = FIN / 32;
    __shared__ __align__(16) ushort wt[64 * FIN];
    char* wtb = (char*)wt;
    for (int i = threadIdx.x; i < FIN * 64; i += 256) {
        int k = i >> 6, c = i & 63;            // W[i] = W[k][c], coalesced global read
        int byte = c * (FIN * 2) + k * 2;
        byte ^= ((c & 7) << 4);
        *(ushort*)(wtb + byte) = f2bf(W[i]);
    }
    __syncthreads();

    int lane = threadIdx.x & 63;
    int wv = threadIdx.x >> 6;
    int lo = lane & 15, hi = lane >> 4;

    // B-frags from swizzled LDS
    bf16x8 bfrag[NKC][4];
#pragma unroll
    for (int kc = 0; kc < NKC; ++kc) {
#pragma unroll
        for (int nc = 0; nc < 4; ++nc) {
            int c = nc * 16 + lo;
            int byte = c * (FIN * 2) + (kc * 32 + 8 * hi) * 2;
            byte ^= ((c & 7) << 4);
            bfrag[kc][nc] = *(const bf16x8*)(wtb + byte);
        }
    }

    int arow = blockIdx.x * 64 + wv * 16 + lo;  // row this lane's A-frag comes from
    f32x4 acc[4] = {{0.f, 0.f, 0.f, 0.f}, {0.f, 0.f, 0.f, 0.f},
                    {0.f, 0.f, 0.f, 0.f}, {0.f, 0.f, 0.f, 0.f}};
    const TIN* xr = X + (size_t)arow * FIN;
#pragma unroll
    for (int kc = 0; kc < NKC; ++kc) {
        int koff = kc * 32 + 8 * hi;
        bf16x8 af = {0, 0, 0, 0, 0, 0, 0, 0};
        if (arow < n) {
            if constexpr (sizeof(TIN) == 4) {
                float4 va = *reinterpret_cast<const float4*>((const float*)xr + koff);
                float4 vb = *reinterpret_cast<const float4*>((const float*)xr + koff + 4);
                af[0] = (short)f2bf(va.x); af[1] = (short)f2bf(va.y);
                af[2] = (short)f2bf(va.z); af[3] = (short)f2bf(va.w);
                af[4] = (short)f2bf(vb.x); af[5] = (short)f2bf(vb.y);
                af[6] = (short)f2bf(vb.z); af[7] = (short)f2bf(vb.w);
            } else {
                af = *reinterpret_cast<const bf16x8*>((const ushort*)xr + koff);
            }
        }
#pragma unroll
        for (int nc = 0; nc < 4; ++nc) {
            acc[nc] = __builtin_amdgcn_mfma_f32_16x16x32_bf16(af, bfrag[kc][nc], acc[nc], 0, 0, 0);
        }
    }

    // epilogue: D[row=4*hi+j][col=nc*16+lo] -> fp8
    int orow0 = blockIdx.x * 64 + wv * 16 + 4 * hi;
#pragma unroll
    for (int j = 0; j < 4; ++j) {
        int orow = orow0 + j;
        if (orow < n) {
            float dv = dinv[orow];
            unsigned char* outr = XWB + (size_t)orow * 64 + lo;
#pragma unroll
            for (int nc = 0; nc < 4; ++nc) {
                outr[nc * 16] = f2fp8(dv * acc[nc][j]);
            }
        }
    }
}

// ---------------- quad-row CSR aggregation (fp8 gathers, fp32 accum, bf16 out) ----------------
// 4 rows per wave: q = lane>>4 picks the row, 16 lanes x 4 feats (uint = 4xfp8).
// One wave gather instruction = 256B payload = one 64B row-line for EACH of 4 rows.
__global__ __launch_bounds__(256) void agg_quad_kernel(const unsigned char* __restrict__ XWB,
                                                       const int* __restrict__ rowptr,
                                                       const int* __restrict__ col,
                                                       const float* __restrict__ dinv,
                                                       const float* __restrict__ bias,
                                                       ushort* __restrict__ OUT, int n) {
    int lane = threadIdx.x & 63;
    int q = lane >> 4;
    int sl = lane & 15;
    int wid = (blockIdx.x * blockDim.x + threadIdx.x) >> 6;
    int nw = (gridDim.x * blockDim.x) >> 6;
    float b0 = bias[sl * 4 + 0], b1 = bias[sl * 4 + 1];
    float b2 = bias[sl * 4 + 2], b3 = bias[sl * 4 + 3];
    int nquads = (n + 3) >> 2;
    for (int qi = wid; qi < nquads; qi += nw) {
        int i = qi * 4 + q;
        bool valid = i < n;
        int p = 0, pend = 0;
        float A0 = 0.f, A1 = 0.f, A2 = 0.f, A3 = 0.f;
        float B0 = 0.f, B1 = 0.f, B2 = 0.f, B3 = 0.f;
        float C0 = 0.f, C1 = 0.f, C2 = 0.f, C3 = 0.f;
        float D0 = 0.f, D1 = 0.f, D2 = 0.f, D3 = 0.f;
        if (valid) {
            p = rowptr[i];
            pend = rowptr[i + 1];
            unsigned int v = *reinterpret_cast<const unsigned int*>(XWB + (size_t)i * 64 + sl * 4);
            f32x2 l = __builtin_amdgcn_cvt_pk_f32_fp8(v, false);
            f32x2 h = __builtin_amdgcn_cvt_pk_f32_fp8(v, true);
            A0 = l.x; A1 = l.y; A2 = h.x; A3 = h.y;  // self-loop (pre-scaled)
        }
        for (; p + 4 <= pend; p += 4) {
            int c0 = col[p], c1 = col[p + 1], c2 = col[p + 2], c3 = col[p + 3];
            unsigned int v0 = *reinterpret_cast<const unsigned int*>(XWB + (size_t)c0 * 64 + sl * 4);
            unsigned int v1 = *reinterpret_cast<const unsigned int*>(XWB + (size_t)c1 * 64 + sl * 4);
            unsigned int v2 = *reinterpret_cast<const unsigned int*>(XWB + (size_t)c2 * 64 + sl * 4);
            unsigned int v3 = *reinterpret_cast<const unsigned int*>(XWB + (size_t)c3 * 64 + sl * 4);
            f32x2 l0 = __builtin_amdgcn_cvt_pk_f32_fp8(v0, false);
            f32x2 h0 = __builtin_amdgcn_cvt_pk_f32_fp8(v0, true);
            f32x2 l1 = __builtin_amdgcn_cvt_pk_f32_fp8(v1, false);
            f32x2 h1 = __builtin_amdgcn_cvt_pk_f32_fp8(v1, true);
            f32x2 l2 = __builtin_amdgcn_cvt_pk_f32_fp8(v2, false);
            f32x2 h2 = __builtin_amdgcn_cvt_pk_f32_fp8(v2, true);
            f32x2 l3 = __builtin_amdgcn_cvt_pk_f32_fp8(v3, false);
            f32x2 h3 = __builtin_amdgcn_cvt_pk_f32_fp8(v3, true);
            A0 += l0.x; A1 += l0.y; A2 += h0.x; A3 += h0.y;
            B0 += l1.x; B1 += l1.y; B2 += h1.x; B3 += h1.y;
            C0 += l2.x; C1 += l2.y; C2 += h2.x; C3 += h2.y;
            D0 += l3.x; D1 += l3.y; D2 += h3.x; D3 += h3.y;
        }
        for (; p < pend; ++p) {
            unsigned int v = *reinterpret_cast<const unsigned int*>(XWB + (size_t)col[p] * 64 + sl * 4);
            f32x2 l = __builtin_amdgcn_cvt_pk_f32_fp8(v, false);
            f32x2 h = __builtin_amdgcn_cvt_pk_f32_fp8(v, true);
            A0 += l.x; A1 += l.y; A2 += h.x; A3 += h.y;
        }
        if (valid) {
            float f0 = (A0 + B0) + (C0 + D0);
            float f1 = (A1 + B1) + (C1 + D1);
            float f2 = (A2 + B2) + (C2 + D2);
            float f3 = (A3 + B3) + (C3 + D3);
            float di = dinv[i];
            f0 = fmaxf(di * f0 + b0, 0.f);
            f1 = fmaxf(di * f1 + b1, 0.f);
            f2 = fmaxf(di * f2 + b2, 0.f);
            f3 = fmaxf(di * f3 + b3, 0.f);
            unsigned int w0 = (unsigned int)f2bf(f0) | ((unsigned int)f2bf(f1) << 16);
            unsigned int w1 = (unsigned int)f2bf(f2) | ((unsigned int)f2bf(f3) << 16);
            *reinterpret_cast<uint2*>(OUT + (size_t)i * 64 + sl * 4) = make_uint2(w0, w1);
        }
    }
}

// ---------------- mean pool (batch is sorted; H is bf16) ----------------
__global__ void pool_kernel(const ushort* __restrict__ H, const int* __restrict__ batch,
                            float* __restrict__ pooled, int n) {
    int g = blockIdx.x;
    int lo = 0, hi = n;
    while (lo < hi) { int mid = (lo + hi) >> 1; if (batch[mid] < g) lo = mid + 1; else hi = mid; }
    int start = lo;
    lo = 0; hi = n;
    while (lo < hi) { int mid = (lo + hi) >> 1; if (batch[mid] < g + 1) lo = mid + 1; else hi = mid; }
    int end = lo;

    int lane = threadIdx.x & 63;
    int w = threadIdx.x >> 6;
    __shared__ float part[4][64];
    float acc = 0.f;
    for (int i = start + w; i < end; i += 4) acc += bf2f(H[(size_t)i * 64 + lane]);
    part[w][lane] = acc;
    __syncthreads();
    if (w == 0) {
        float s = part[0][lane] + part[1][lane] + part[2][lane] + part[3][lane];
        float cnt = (float)(end - start);
        pooled[g * 64 + lane] = s / fmaxf(cnt, 1.0f);
    }
}

// ---------------- head ----------------
__global__ void head_kernel(const float* __restrict__ pooled, const float* __restrict__ fcw,
                            const float* __restrict__ fcb, float* __restrict__ out) {
    __shared__ float w[64 * N_CLASSES];
    __shared__ float bb[N_CLASSES];
    for (int i = threadIdx.x; i < 64 * N_CLASSES; i += blockDim.x) w[i] = fcw[i];
    if (threadIdx.x < N_CLASSES) bb[threadIdx.x] = fcb[threadIdx.x];
    __syncthreads();
    int g = threadIdx.x;  // 256 threads, one per graph
    float logits[N_CLASSES];
    float m = -1e30f;
    const float* pr = pooled + g * 64;
    for (int c = 0; c < N_CLASSES; ++c) {
        float acc = bb[c];
        for (int k = 0; k < 64; ++k) acc += pr[k] * w[k * N_CLASSES + c];
        logits[c] = acc;
        m = fmaxf(m, acc);
    }
    float se = 0.f;
    for (int c = 0; c < N_CLASSES; ++c) se += expf(logits[c] - m);
    float lse = m + logf(se);
    for (int c = 0; c < N_CLASSES; ++c) out[g * N_CLASSES + c] = logits[c] - lse;
}

extern "C" void kernel_launch(void* const* d_in, const int* in_sizes, int n_in,
                              void* d_out, int out_size, void* d_ws, size_t ws_size,
                              hipStream_t stream) {
    const float* x    = (const float*)d_in[0];
    const float* w1   = (const float*)d_in[1];
    const float* b1   = (const float*)d_in[2];
    const float* w2   = (const float*)d_in[3];
    const float* b2   = (const float*)d_in[4];
    const float* w3   = (const float*)d_in[5];
    const float* b3   = (const float*)d_in[6];
    const float* fcw  = (const float*)d_in[7];
    const float* fcb  = (const float*)d_in[8];
    const int*   ei   = (const int*)d_in[9];
    const int*   batch = (const int*)d_in[10];

    const int N = in_sizes[10];       // 100000
    const int E = in_sizes[9] / 2;    // 1600000
    const int* src = ei;
    const int* dst = ei + E;

    const int NBUCK = (N + (1 << NB_SHIFT) - 1) >> NB_SHIFT;   // 196
    const int NBLK = (E + EDGE_CHUNK - 1) / EDGE_CHUNK;        // 391

    char* ws = (char*)d_ws;
    size_t off = 0;
    auto alloc = [&](size_t bytes) -> void* {
        void* p = ws + off;
        off += (bytes + 255) & ~(size_t)255;
        return p;
    };
    int*          rowptr = (int*)alloc(((size_t)N + 1) * 4);
    int*          cnt    = (int*)alloc((size_t)MAXNB * NBLK * 4);
    int*          cbase  = (int*)alloc((size_t)MAXNB * NBLK * 4);
    int*          btot   = (int*)alloc(256 * 4);
    int*          sbase  = (int*)alloc(260 * 4);
    unsigned int* stage  = (unsigned int*)alloc((size_t)E * 4);  // packed src|li<<23
    int*          col    = (int*)alloc((size_t)E * 4);
    float*        dinv   = (float*)alloc((size_t)N * 4);
    unsigned char* xwb   = (unsigned char*)alloc((size_t)N * 64);  // fp8 pre-scaled table
    ushort*       hbuf   = (ushort*)alloc((size_t)N * 64 * 2);     // bf16 h
    float*        pooled = (float*)alloc((size_t)N_GRAPHS * 64 * 4);
    (void)ws_size;

    const int GB = 2048;

    cnt_kernel<<<NBLK, 256, 0, stream>>>(dst, cnt, E, NBLK);
    btot_kernel<<<NBUCK, 256, 0, stream>>>(cnt, btot, NBLK);
    sscan_kernel<<<1, 256, 0, stream>>>(btot, sbase, NBUCK);
    cbase_kernel<<<NBUCK, 256, 0, stream>>>(cnt, sbase, cbase, NBLK);
    place_kernel<<<NBLK, 256, 0, stream>>>(src, dst, cbase, stage, E, NBLK, NBUCK);
    finalize_kernel<<<NBUCK, 256, 0, stream>>>(stage, sbase, rowptr, dinv, col, N, NBUCK);

    int gtiles = (N + 63) / 64;  // 1563 blocks, 64 rows each

    // layer 1
    gemm_mfma_kernel<128, float><<<gtiles, 256, 0, stream>>>(x, w1, dinv, xwb, N);
    agg_quad_kernel<<<GB, 256, 0, stream>>>(xwb, rowptr, col, dinv, b1, hbuf, N);
    // layer 2
    gemm_mfma_kernel<64, ushort><<<gtiles, 256, 0, stream>>>(hbuf, w2, dinv, xwb, N);
    agg_quad_kernel<<<GB, 256, 0, stream>>>(xwb, rowptr, col, dinv, b2, hbuf, N);
    // layer 3
    gemm_mfma_kernel<64, ushort><<<gtiles, 256, 0, stream>>>(hbuf, w3, dinv, xwb, N);
    agg_quad_kernel<<<GB, 256, 0, stream>>>(xwb, rowptr, col, dinv, b3, hbuf, N);

    pool_kernel<<<N_GRAPHS, 256, 0, stream>>>(hbuf, batch, pooled, N);
    head_kernel<<<1, 256, 0, stream>>>(pooled, fcw, fcb, (float*)d_out);
}

// Round 16
// 215.418 us; speedup vs baseline: 1.6636x; 1.0093x over previous
//
#include <hip/hip_runtime.h>
#include <hip/hip_bf16.h>

// GCN: 3x GCNConv(relu) + mean-pool + linear + log_softmax
// N=100000 nodes, E=1600000 edges, F=128 -> 64 -> 64 -> 64, 256 graphs, 15 classes.
//
// Round 16 structure (= r15 + exact-fit agg grid + 8-deep gather unroll):
//  - gather table xwb in FP8 e4m3 (OCP), pre-scaled: xwb[i] = fp8(dinv[i]*(h@W)[i])
//    (r15: agg L2-miss line traffic halved; absmax unchanged 0.0156)
//  - agg: 4 rows/wave x 16 lanes x 4 feats; grid 3125 blocks = exactly 2 quads/wave
//    (was 2048 -> 3.05 quads/wave, ragged +31% tail); 8 gathers in flight
//  - stage packed to 4B: src | (dst&511)<<23
//  - build: zero global atomics; gemm: mfma_f32_16x16x32_bf16

#define N_GRAPHS 256
#define HIDDEN 64
#define N_CLASSES 15
#define NB_SHIFT 9        // bucket = 512 consecutive nodes
#define MAXNB 256         // supports N <= 131072
#define EDGE_CHUNK 4096   // edges per block in cnt/place (16 per thread)

typedef __attribute__((ext_vector_type(8))) short bf16x8;
typedef __attribute__((ext_vector_type(4))) float f32x4;
typedef __attribute__((ext_vector_type(2))) float f32x2;

__device__ __forceinline__ float bf2f(ushort u) {
    return __uint_as_float(((unsigned int)u) << 16);
}
__device__ __forceinline__ ushort f2bf(float f) {
    __hip_bfloat16 h = __float2bfloat16(f);  // RNE
    return *reinterpret_cast<ushort*>(&h);
}
__device__ __forceinline__ unsigned char f2fp8(float f) {
    int p = __builtin_amdgcn_cvt_pk_fp8_f32(f, f, 0, false);
    return (unsigned char)(p & 0xff);
}

// ---------------- per-(block,bucket) counts (LDS only) ----------------
__global__ __launch_bounds__(256) void cnt_kernel(const int* __restrict__ dst,
                                                  int* __restrict__ cnt, int E, int nblk) {
    __shared__ int lcnt[MAXNB];
    int blk = blockIdx.x;
    for (int i = threadIdx.x; i < MAXNB; i += 256) lcnt[i] = 0;
    __syncthreads();
    int base = blk * EDGE_CHUNK;
#pragma unroll
    for (int it = 0; it < EDGE_CHUNK / 256; ++it) {
        int e = base + it * 256 + threadIdx.x;
        if (e < E) atomicAdd(&lcnt[dst[e] >> NB_SHIFT], 1);
    }
    __syncthreads();
    for (int b = threadIdx.x; b < MAXNB; b += 256) cnt[b * nblk + blk] = lcnt[b];
}

// ---------------- bucket totals ----------------
__global__ __launch_bounds__(256) void btot_kernel(const int* __restrict__ cnt,
                                                   int* __restrict__ btot, int nblk) {
    int b = blockIdx.x;
    __shared__ int ls[256];
    int s = 0;
    for (int i = threadIdx.x; i < nblk; i += 256) s += cnt[b * nblk + i];
    ls[threadIdx.x] = s;
    __syncthreads();
    for (int off = 128; off > 0; off >>= 1) {
        if (threadIdx.x < off) ls[threadIdx.x] += ls[threadIdx.x + off];
        __syncthreads();
    }
    if (threadIdx.x == 0) btot[b] = ls[0];
}

// ---------------- tiny exclusive scan of bucket totals -> sbase[0..nb] ----------------
__global__ __launch_bounds__(256) void sscan_kernel(const int* __restrict__ btot,
                                                    int* __restrict__ sbase, int nb) {
    __shared__ int s[256];
    int t = threadIdx.x;
    s[t] = (t < nb) ? btot[t] : 0;
    __syncthreads();
    for (int off = 1; off < 256; off <<= 1) {
        int v = (t >= off) ? s[t - off] : 0;
        __syncthreads();
        s[t] += v;
        __syncthreads();
    }
    if (t < nb) sbase[t] = (t == 0) ? 0 : s[t - 1];
    if (t == 0) sbase[nb] = s[255];
}

// ---------------- cbase[b][blk] = sbase[b] + excl_scan_blk(cnt[b][:]) ----------------
__global__ __launch_bounds__(256) void cbase_kernel(const int* __restrict__ cnt,
                                                    const int* __restrict__ sbase,
                                                    int* __restrict__ cbase, int nblk) {
    int b = blockIdx.x;
    __shared__ int ls[256];
    int t = threadIdx.x;
    int chunk = (nblk + 255) / 256;
    int start = t * chunk;
    int end = start + chunk;
    if (end > nblk) end = nblk;
    int s = 0;
    for (int i = start; i < end; ++i) s += cnt[b * nblk + i];
    ls[t] = s;
    __syncthreads();
    for (int off = 1; off < 256; off <<= 1) {
        int v = (t >= off) ? ls[t - off] : 0;
        __syncthreads();
        ls[t] += v;
        __syncthreads();
    }
    int run = sbase[b] + ((t == 0) ? 0 : ls[t - 1]);
    for (int i = start; i < end; ++i) {
        cbase[b * nblk + i] = run;
        run += cnt[b * nblk + i];
    }
}

// ---------------- placement: LDS tickets, bucket-major packed staging ----------------
__global__ __launch_bounds__(256) void place_kernel(const int* __restrict__ src,
                                                    const int* __restrict__ dst,
                                                    const int* __restrict__ cbase,
                                                    unsigned int* __restrict__ stage,
                                                    int E, int nblk, int nb) {
    __shared__ int lpos[MAXNB];
    int blk = blockIdx.x;
    for (int b = threadIdx.x; b < nb; b += 256) lpos[b] = cbase[b * nblk + blk];
    __syncthreads();
    int base = blk * EDGE_CHUNK;
#pragma unroll
    for (int it = 0; it < EDGE_CHUNK / 256; ++it) {
        int e = base + it * 256 + threadIdx.x;
        if (e < E) {
            int d = dst[e], s = src[e];
            int slot = atomicAdd(&lpos[d >> NB_SHIFT], 1);  // LDS ticket
            stage[slot] = (unsigned int)s | ((unsigned int)(d & ((1 << NB_SHIFT) - 1)) << 23);
        }
    }
}

// ---------------- finalize: per-bucket deg/rowptr/dinv + CSR col (all bucket-local) ----------------
__global__ __launch_bounds__(256) void finalize_kernel(const unsigned int* __restrict__ stage,
                                                       const int* __restrict__ sbase,
                                                       int* __restrict__ rowptr,
                                                       float* __restrict__ dinv,
                                                       int* __restrict__ col, int n, int nb) {
    int b = blockIdx.x;
    int t = threadIdx.x;
    int node0 = b << NB_SHIFT;
    int lo = sbase[b], hi = sbase[b + 1];

    __shared__ int lcnt[1 << NB_SHIFT];
    __shared__ int lrow[1 << NB_SHIFT];
    __shared__ int ls[256];

    lcnt[t] = 0;
    lcnt[t + 256] = 0;
    __syncthreads();
    // pass 1: local degree histogram
    for (int e = lo + t; e < hi; e += 256) {
        atomicAdd(&lcnt[stage[e] >> 23], 1);
    }
    __syncthreads();
    // local exclusive scan over 512 counters (2 per thread)
    int c0 = lcnt[2 * t], c1 = lcnt[2 * t + 1];
    ls[t] = c0 + c1;
    __syncthreads();
    for (int off = 1; off < 256; off <<= 1) {
        int v = (t >= off) ? ls[t - off] : 0;
        __syncthreads();
        ls[t] += v;
        __syncthreads();
    }
    int bse = (t == 0) ? 0 : ls[t - 1];
    lrow[2 * t] = bse;
    lrow[2 * t + 1] = bse + c0;
    // rowptr / dinv
    int i0 = node0 + 2 * t;
    if (i0 < n) {
        rowptr[i0] = lo + bse;
        dinv[i0] = rsqrtf((float)(c0 + 1));  // +1 = self-loop
    }
    if (i0 + 1 < n) {
        rowptr[i0 + 1] = lo + bse + c0;
        dinv[i0 + 1] = rsqrtf((float)(c1 + 1));
    }
    if (b == nb - 1 && t == 0) rowptr[n] = hi;
    __syncthreads();
    // reset counters for ticketing
    lcnt[t] = 0;
    lcnt[t + 256] = 0;
    __syncthreads();
    // pass 2: place col within this bucket's contiguous window [lo, hi)
    for (int e = lo + t; e < hi; e += 256) {
        unsigned int v = stage[e];
        int li = v >> 23;
        int k = atomicAdd(&lcnt[li], 1);  // LDS ticket
        col[lo + lrow[li] + k] = (int)(v & 0x7fffff);
    }
}

// ---------------- MFMA GEMM: XWB(fp8) = dinv .* (X @ W) ----------------
// block = 256 threads (4 waves); each wave computes 16 rows x 64 cols; block = 64 rows.
template <int FIN, typename TIN>
__global__ __launch_bounds__(256) void gemm_mfma_kernel(const TIN* __restrict__ X,
                                                        const float* __restrict__ W,
                                                        const float* __restrict__ dinv,
                                                        unsigned char* __restrict__ XWB, int n) {
    constexpr int NKC = FIN / 32;
    __shared__ __align__(16) ushort wt[64 * FIN];
    char* wtb = (char*)wt;
    for (int i = threadIdx.x; i < FIN * 64; i += 256) {
        int k = i >> 6, c = i & 63;            // W[i] = W[k][c], coalesced global read
        int byte = c * (FIN * 2) + k * 2;
        byte ^= ((c & 7) << 4);
        *(ushort*)(wtb + byte) = f2bf(W[i]);
    }
    __syncthreads();

    int lane = threadIdx.x & 63;
    int wv = threadIdx.x >> 6;
    int lo = lane & 15, hi = lane >> 4;

    // B-frags from swizzled LDS
    bf16x8 bfrag[NKC][4];
#pragma unroll
    for (int kc = 0; kc < NKC; ++kc) {
#pragma unroll
        for (int nc = 0; nc < 4; ++nc) {
            int c = nc * 16 + lo;
            int byte = c * (FIN * 2) + (kc * 32 + 8 * hi) * 2;
            byte ^= ((c & 7) << 4);
            bfrag[kc][nc] = *(const bf16x8*)(wtb + byte);
        }
    }

    int arow = blockIdx.x * 64 + wv * 16 + lo;  // row this lane's A-frag comes from
    f32x4 acc[4] = {{0.f, 0.f, 0.f, 0.f}, {0.f, 0.f, 0.f, 0.f},
                    {0.f, 0.f, 0.f, 0.f}, {0.f, 0.f, 0.f, 0.f}};
    const TIN* xr = X + (size_t)arow * FIN;
#pragma unroll
    for (int kc = 0; kc < NKC; ++kc) {
        int koff = kc * 32 + 8 * hi;
        bf16x8 af = {0, 0, 0, 0, 0, 0, 0, 0};
        if (arow < n) {
            if constexpr (sizeof(TIN) == 4) {
                float4 va = *reinterpret_cast<const float4*>((const float*)xr + koff);
                float4 vb = *reinterpret_cast<const float4*>((const float*)xr + koff + 4);
                af[0] = (short)f2bf(va.x); af[1] = (short)f2bf(va.y);
                af[2] = (short)f2bf(va.z); af[3] = (short)f2bf(va.w);
                af[4] = (short)f2bf(vb.x); af[5] = (short)f2bf(vb.y);
                af[6] = (short)f2bf(vb.z); af[7] = (short)f2bf(vb.w);
            } else {
                af = *reinterpret_cast<const bf16x8*>((const ushort*)xr + koff);
            }
        }
#pragma unroll
        for (int nc = 0; nc < 4; ++nc) {
            acc[nc] = __builtin_amdgcn_mfma_f32_16x16x32_bf16(af, bfrag[kc][nc], acc[nc], 0, 0, 0);
        }
    }

    // epilogue: D[row=4*hi+j][col=nc*16+lo] -> fp8
    int orow0 = blockIdx.x * 64 + wv * 16 + 4 * hi;
#pragma unroll
    for (int j = 0; j < 4; ++j) {
        int orow = orow0 + j;
        if (orow < n) {
            float dv = dinv[orow];
            unsigned char* outr = XWB + (size_t)orow * 64 + lo;
#pragma unroll
            for (int nc = 0; nc < 4; ++nc) {
                outr[nc * 16] = f2fp8(dv * acc[nc][j]);
            }
        }
    }
}

// ---------------- quad-row CSR aggregation (fp8 gathers, fp32 accum, bf16 out) ----------------
// 4 rows per wave: q = lane>>4 picks the row, 16 lanes x 4 feats (uint = 4xfp8).
// 8 gathers issued before any convert/accumulate (32 outstanding per wave).
__global__ __launch_bounds__(256) void agg_quad_kernel(const unsigned char* __restrict__ XWB,
                                                       const int* __restrict__ rowptr,
                                                       const int* __restrict__ col,
                                                       const float* __restrict__ dinv,
                                                       const float* __restrict__ bias,
                                                       ushort* __restrict__ OUT, int n) {
    int lane = threadIdx.x & 63;
    int q = lane >> 4;
    int sl = lane & 15;
    int wid = (blockIdx.x * blockDim.x + threadIdx.x) >> 6;
    int nw = (gridDim.x * blockDim.x) >> 6;
    float b0 = bias[sl * 4 + 0], b1 = bias[sl * 4 + 1];
    float b2 = bias[sl * 4 + 2], b3 = bias[sl * 4 + 3];
    int nquads = (n + 3) >> 2;
    for (int qi = wid; qi < nquads; qi += nw) {
        int i = qi * 4 + q;
        bool valid = i < n;
        int p = 0, pend = 0;
        float A0 = 0.f, A1 = 0.f, A2 = 0.f, A3 = 0.f;
        float B0 = 0.f, B1 = 0.f, B2 = 0.f, B3 = 0.f;
        float C0 = 0.f, C1 = 0.f, C2 = 0.f, C3 = 0.f;
        float D0 = 0.f, D1 = 0.f, D2 = 0.f, D3 = 0.f;
        if (valid) {
            p = rowptr[i];
            pend = rowptr[i + 1];
            unsigned int v = *reinterpret_cast<const unsigned int*>(XWB + (size_t)i * 64 + sl * 4);
            f32x2 l = __builtin_amdgcn_cvt_pk_f32_fp8(v, false);
            f32x2 h = __builtin_amdgcn_cvt_pk_f32_fp8(v, true);
            A0 = l.x; A1 = l.y; A2 = h.x; A3 = h.y;  // self-loop (pre-scaled)
        }
        // 8-deep: issue 8 gathers, then convert+accumulate into 4 groups
        for (; p + 8 <= pend; p += 8) {
            int c0 = col[p], c1 = col[p + 1], c2 = col[p + 2], c3 = col[p + 3];
            int c4 = col[p + 4], c5 = col[p + 5], c6 = col[p + 6], c7 = col[p + 7];
            unsigned int v0 = *reinterpret_cast<const unsigned int*>(XWB + (size_t)c0 * 64 + sl * 4);
            unsigned int v1 = *reinterpret_cast<const unsigned int*>(XWB + (size_t)c1 * 64 + sl * 4);
            unsigned int v2 = *reinterpret_cast<const unsigned int*>(XWB + (size_t)c2 * 64 + sl * 4);
            unsigned int v3 = *reinterpret_cast<const unsigned int*>(XWB + (size_t)c3 * 64 + sl * 4);
            unsigned int v4 = *reinterpret_cast<const unsigned int*>(XWB + (size_t)c4 * 64 + sl * 4);
            unsigned int v5 = *reinterpret_cast<const unsigned int*>(XWB + (size_t)c5 * 64 + sl * 4);
            unsigned int v6 = *reinterpret_cast<const unsigned int*>(XWB + (size_t)c6 * 64 + sl * 4);
            unsigned int v7 = *reinterpret_cast<const unsigned int*>(XWB + (size_t)c7 * 64 + sl * 4);
            f32x2 l0 = __builtin_amdgcn_cvt_pk_f32_fp8(v0, false);
            f32x2 h0 = __builtin_amdgcn_cvt_pk_f32_fp8(v0, true);
            f32x2 l1 = __builtin_amdgcn_cvt_pk_f32_fp8(v1, false);
            f32x2 h1 = __builtin_amdgcn_cvt_pk_f32_fp8(v1, true);
            f32x2 l2 = __builtin_amdgcn_cvt_pk_f32_fp8(v2, false);
            f32x2 h2 = __builtin_amdgcn_cvt_pk_f32_fp8(v2, true);
            f32x2 l3 = __builtin_amdgcn_cvt_pk_f32_fp8(v3, false);
            f32x2 h3 = __builtin_amdgcn_cvt_pk_f32_fp8(v3, true);
            f32x2 l4 = __builtin_amdgcn_cvt_pk_f32_fp8(v4, false);
            f32x2 h4 = __builtin_amdgcn_cvt_pk_f32_fp8(v4, true);
            f32x2 l5 = __builtin_amdgcn_cvt_pk_f32_fp8(v5, false);
            f32x2 h5 = __builtin_amdgcn_cvt_pk_f32_fp8(v5, true);
            f32x2 l6 = __builtin_amdgcn_cvt_pk_f32_fp8(v6, false);
            f32x2 h6 = __builtin_amdgcn_cvt_pk_f32_fp8(v6, true);
            f32x2 l7 = __builtin_amdgcn_cvt_pk_f32_fp8(v7, false);
            f32x2 h7 = __builtin_amdgcn_cvt_pk_f32_fp8(v7, true);
            A0 += l0.x + l4.x; A1 += l0.y + l4.y; A2 += h0.x + h4.x; A3 += h0.y + h4.y;
            B0 += l1.x + l5.x; B1 += l1.y + l5.y; B2 += h1.x + h5.x; B3 += h1.y + h5.y;
            C0 += l2.x + l6.x; C1 += l2.y + l6.y; C2 += h2.x + h6.x; C3 += h2.y + h6.y;
            D0 += l3.x + l7.x; D1 += l3.y + l7.y; D2 += h3.x + h7.x; D3 += h3.y + h7.y;
        }
        for (; p + 4 <= pend; p += 4) {
            int c0 = col[p], c1 = col[p + 1], c2 = col[p + 2], c3 = col[p + 3];
            unsigned int v0 = *reinterpret_cast<const unsigned int*>(XWB + (size_t)c0 * 64 + sl * 4);
            unsigned int v1 = *reinterpret_cast<const unsigned int*>(XWB + (size_t)c1 * 64 + sl * 4);
            unsigned int v2 = *reinterpret_cast<const unsigned int*>(XWB + (size_t)c2 * 64 + sl * 4);
            unsigned int v3 = *reinterpret_cast<const unsigned int*>(XWB + (size_t)c3 * 64 + sl * 4);
            f32x2 l0 = __builtin_amdgcn_cvt_pk_f32_fp8(v0, false);
            f32x2 h0 = __builtin_amdgcn_cvt_pk_f32_fp8(v0, true);
            f32x2 l1 = __builtin_amdgcn_cvt_pk_f32_fp8(v1, false);
            f32x2 h1 = __builtin_amdgcn_cvt_pk_f32_fp8(v1, true);
            f32x2 l2 = __builtin_amdgcn_cvt_pk_f32_fp8(v2, false);
            f32x2 h2 = __builtin_amdgcn_cvt_pk_f32_fp8(v2, true);
            f32x2 l3 = __builtin_amdgcn_cvt_pk_f32_fp8(v3, false);
            f32x2 h3 = __builtin_amdgcn_cvt_pk_f32_fp8(v3, true);
            A0 += l0.x; A1 += l0.y; A2 += h0.x; A3 += h0.y;
            B0 += l1.x; B1 += l1.y; B2 += h1.x; B3 += h1.y;
            C0 += l2.x; C1 += l2.y; C2 += h2.x; C3 += h2.y;
            D0 += l3.x; D1 += l3.y; D2 += h3.x; D3 += h3.y;
        }
        for (; p < pend; ++p) {
            unsigned int v = *reinterpret_cast<const unsigned int*>(XWB + (size_t)col[p] * 64 + sl * 4);
            f32x2 l = __builtin_amdgcn_cvt_pk_f32_fp8(v, false);
            f32x2 h = __builtin_amdgcn_cvt_pk_f32_fp8(v, true);
            A0 += l.x; A1 += l.y; A2 += h.x; A3 += h.y;
        }
        if (valid) {
            float f0 = (A0 + B0) + (C0 + D0);
            float f1 = (A1 + B1) + (C1 + D1);
            float f2 = (A2 + B2) + (C2 + D2);
            float f3 = (A3 + B3) + (C3 + D3);
            float di = dinv[i];
            f0 = fmaxf(di * f0 + b0, 0.f);
            f1 = fmaxf(di * f1 + b1, 0.f);
            f2 = fmaxf(di * f2 + b2, 0.f);
            f3 = fmaxf(di * f3 + b3, 0.f);
            unsigned int w0 = (unsigned int)f2bf(f0) | ((unsigned int)f2bf(f1) << 16);
            unsigned int w1 = (unsigned int)f2bf(f2) | ((unsigned int)f2bf(f3) << 16);
            *reinterpret_cast<uint2*>(OUT + (size_t)i * 64 + sl * 4) = make_uint2(w0, w1);
        }
    }
}

// ---------------- mean pool (batch is sorted; H is bf16) ----------------
__global__ void pool_kernel(const ushort* __restrict__ H, const int* __restrict__ batch,
                            float* __restrict__ pooled, int n) {
    int g = blockIdx.x;
    int lo = 0, hi = n;
    while (lo < hi) { int mid = (lo + hi) >> 1; if (batch[mid] < g) lo = mid + 1; else hi = mid; }
    int start = lo;
    lo = 0; hi = n;
    while (lo < hi) { int mid = (lo + hi) >> 1; if (batch[mid] < g + 1) lo = mid + 1; else hi = mid; }
    int end = lo;

    int lane = threadIdx.x & 63;
    int w = threadIdx.x >> 6;
    __shared__ float part[4][64];
    float acc = 0.f;
    for (int i = start + w; i < end; i += 4) acc += bf2f(H[(size_t)i * 64 + lane]);
    part[w][lane] = acc;
    __syncthreads();
    if (w == 0) {
        float s = part[0][lane] + part[1][lane] + part[2][lane] + part[3][lane];
        float cnt = (float)(end - start);
        pooled[g * 64 + lane] = s / fmaxf(cnt, 1.0f);
    }
}

// ---------------- head ----------------
__global__ void head_kernel(const float* __restrict__ pooled, const float* __restrict__ fcw,
                            const float* __restrict__ fcb, float* __restrict__ out) {
    __shared__ float w[64 * N_CLASSES];
    __shared__ float bb[N_CLASSES];
    for (int i = threadIdx.x; i < 64 * N_CLASSES; i += blockDim.x) w[i] = fcw[i];
    if (threadIdx.x < N_CLASSES) bb[threadIdx.x] = fcb[threadIdx.x];
    __syncthreads();
    int g = threadIdx.x;  // 256 threads, one per graph
    float logits[N_CLASSES];
    float m = -1e30f;
    const float* pr = pooled + g * 64;
    for (int c = 0; c < N_CLASSES; ++c) {
        float acc = bb[c];
        for (int k = 0; k < 64; ++k) acc += pr[k] * w[k * N_CLASSES + c];
        logits[c] = acc;
        m = fmaxf(m, acc);
    }
    float se = 0.f;
    for (int c = 0; c < N_CLASSES; ++c) se += expf(logits[c] - m);
    float lse = m + logf(se);
    for (int c = 0; c < N_CLASSES; ++c) out[g * N_CLASSES + c] = logits[c] - lse;
}

extern "C" void kernel_launch(void* const* d_in, const int* in_sizes, int n_in,
                              void* d_out, int out_size, void* d_ws, size_t ws_size,
                              hipStream_t stream) {
    const float* x    = (const float*)d_in[0];
    const float* w1   = (const float*)d_in[1];
    const float* b1   = (const float*)d_in[2];
    const float* w2   = (const float*)d_in[3];
    const float* b2   = (const float*)d_in[4];
    const float* w3   = (const float*)d_in[5];
    const float* b3   = (const float*)d_in[6];
    const float* fcw  = (const float*)d_in[7];
    const float* fcb  = (const float*)d_in[8];
    const int*   ei   = (const int*)d_in[9];
    const int*   batch = (const int*)d_in[10];

    const int N = in_sizes[10];       // 100000
    const int E = in_sizes[9] / 2;    // 1600000
    const int* src = ei;
    const int* dst = ei + E;

    const int NBUCK = (N + (1 << NB_SHIFT) - 1) >> NB_SHIFT;   // 196
    const int NBLK = (E + EDGE_CHUNK - 1) / EDGE_CHUNK;        // 391

    char* ws = (char*)d_ws;
    size_t off = 0;
    auto alloc = [&](size_t bytes) -> void* {
        void* p = ws + off;
        off += (bytes + 255) & ~(size_t)255;
        return p;
    };
    int*          rowptr = (int*)alloc(((size_t)N + 1) * 4);
    int*          cnt    = (int*)alloc((size_t)MAXNB * NBLK * 4);
    int*          cbase  = (int*)alloc((size_t)MAXNB * NBLK * 4);
    int*          btot   = (int*)alloc(256 * 4);
    int*          sbase  = (int*)alloc(260 * 4);
    unsigned int* stage  = (unsigned int*)alloc((size_t)E * 4);  // packed src|li<<23
    int*          col    = (int*)alloc((size_t)E * 4);
    float*        dinv   = (float*)alloc((size_t)N * 4);
    unsigned char* xwb   = (unsigned char*)alloc((size_t)N * 64);  // fp8 pre-scaled table
    ushort*       hbuf   = (ushort*)alloc((size_t)N * 64 * 2);     // bf16 h
    float*        pooled = (float*)alloc((size_t)N_GRAPHS * 64 * 4);
    (void)ws_size;

    cnt_kernel<<<NBLK, 256, 0, stream>>>(dst, cnt, E, NBLK);
    btot_kernel<<<NBUCK, 256, 0, stream>>>(cnt, btot, NBLK);
    sscan_kernel<<<1, 256, 0, stream>>>(btot, sbase, NBUCK);
    cbase_kernel<<<NBUCK, 256, 0, stream>>>(cnt, sbase, cbase, NBLK);
    place_kernel<<<NBLK, 256, 0, stream>>>(src, dst, cbase, stage, E, NBLK, NBUCK);
    finalize_kernel<<<NBUCK, 256, 0, stream>>>(stage, sbase, rowptr, dinv, col, N, NBUCK);

    int gtiles = (N + 63) / 64;          // 1563 blocks, 64 rows each
    int atiles = (((N + 3) >> 2) + 7) / 8;  // exact fit: 4 waves x 2 quads = 8 quads/block -> 3125

    // layer 1
    gemm_mfma_kernel<128, float><<<gtiles, 256, 0, stream>>>(x, w1, dinv, xwb, N);
    agg_quad_kernel<<<atiles, 256, 0, stream>>>(xwb, rowptr, col, dinv, b1, hbuf, N);
    // layer 2
    gemm_mfma_kernel<64, ushort><<<gtiles, 256, 0, stream>>>(hbuf, w2, dinv, xwb, N);
    agg_quad_kernel<<<atiles, 256, 0, stream>>>(xwb, rowptr, col, dinv, b2, hbuf, N);
    // layer 3
    gemm_mfma_kernel<64, ushort><<<gtiles, 256, 0, stream>>>(hbuf, w3, dinv, xwb, N);
    agg_quad_kernel<<<atiles, 256, 0, stream>>>(xwb, rowptr, col, dinv, b3, hbuf, N);

    pool_kernel<<<N_GRAPHS, 256, 0, stream>>>(hbuf, batch, pooled, N);
    head_kernel<<<1, 256, 0, stream>>>(pooled, fcw, fcb, (float*)d_out);
}